// Round 1
// baseline (1758.698 us; speedup 1.0000x reference)
//
#include <hip/hip_runtime.h>

// ---------------------------------------------------------------------------
// Hetero GraphSAGE (user<->movie), fp32. CSR built on-device each call.
// ---------------------------------------------------------------------------

constexpr int NU = 100000;   // users
constexpr int NM = 50000;    // movies
constexpr int NE = 4000000;  // edges
constexpr int FU = 24;       // user feat
constexpr int FM = 404;      // movie feat
constexpr int HD = 64;       // hidden
// output: [NM, 3]

static inline size_t alignup(size_t x) { return (x + 255) & ~size_t(255); }

// ---------------- CSR build ----------------

__global__ void hist_kernel(const int* __restrict__ src, const int* __restrict__ dst,
                            int* __restrict__ cnt_u, int* __restrict__ cnt_m) {
  int i = blockIdx.x * blockDim.x + threadIdx.x;
  if (i < NE) {
    atomicAdd(&cnt_u[src[i]], 1);
    atomicAdd(&cnt_m[dst[i]], 1);
  }
}

__global__ __launch_bounds__(1024) void scan_kernel(const int* __restrict__ cnt,
                                                    int* __restrict__ rp, int n) {
  __shared__ int lsum[1024];
  int t = threadIdx.x;
  int per = (n + 1023) >> 10;
  int beg = min(t * per, n);
  int end = min(beg + per, n);
  int s = 0;
  for (int i = beg; i < end; ++i) s += cnt[i];
  lsum[t] = s;
  __syncthreads();
  for (int off = 1; off < 1024; off <<= 1) {
    int v = (t >= off) ? lsum[t - off] : 0;
    __syncthreads();
    lsum[t] += v;
    __syncthreads();
  }
  int run = (t == 0) ? 0 : lsum[t - 1];
  for (int i = beg; i < end; ++i) { rp[i] = run; run += cnt[i]; }
  if (t == 1023) rp[n] = run;
}

__global__ void fill_kernel(const int* __restrict__ src, const int* __restrict__ dst,
                            const int* __restrict__ rp_u, const int* __restrict__ rp_m,
                            int* __restrict__ cu, int* __restrict__ cm,
                            int* __restrict__ csr_u, int* __restrict__ csr_m) {
  int i = blockIdx.x * blockDim.x + threadIdx.x;
  if (i < NE) {
    int s = src[i], d = dst[i];
    int pu = atomicAdd(&cu[s], 1);
    csr_u[rp_u[s] + pu] = d;        // by-user list stores movie ids
    int pm = atomicAdd(&cm[d], 1);
    csr_m[rp_m[d] + pm] = s;        // by-movie list stores user ids
  }
}

// ---------------- input projections ----------------

__global__ void proj_user_kernel(const float* __restrict__ xu, const float* __restrict__ Wu,
                                 const float* __restrict__ bu, float* __restrict__ hu) {
  __shared__ float Wt[FU][HD + 1];   // [k][h], padded
  __shared__ float Xl[16][FU];
  int t = threadIdx.x;
  int lane = t & 63, wg = t >> 6;
  int row0 = blockIdx.x * 16;
  for (int h = wg; h < HD; h += 4)
    if (lane < FU) Wt[lane][h] = Wu[h * FU + lane];
  for (int r = wg; r < 16; r += 4)
    if (lane < FU) Xl[r][lane] = xu[(row0 + r) * FU + lane];
  __syncthreads();
  float b = bu[lane];
  float acc[4] = {0.f, 0.f, 0.f, 0.f};
  for (int k = 0; k < FU; ++k) {
    float w = Wt[k][lane];
#pragma unroll
    for (int j = 0; j < 4; ++j) acc[j] += Xl[wg * 4 + j][k] * w;
  }
#pragma unroll
  for (int j = 0; j < 4; ++j)
    hu[(row0 + wg * 4 + j) * HD + lane] = acc[j] + b;
}

__global__ void proj_movie_kernel(const float* __restrict__ xm, const float* __restrict__ Wm,
                                  const float* __restrict__ bm, float* __restrict__ hm) {
  __shared__ float Wt[64][HD + 1];   // [kk][h], padded
  __shared__ float Xl[16][64];
  int t = threadIdx.x;
  int lane = t & 63, wg = t >> 6;
  int row0 = blockIdx.x * 16;
  float acc[4] = {0.f, 0.f, 0.f, 0.f};
  for (int k0 = 0; k0 < FM; k0 += 64) {
    int kc = min(64, FM - k0);
    __syncthreads();
    for (int h = wg; h < HD; h += 4)
      if (lane < kc) Wt[lane][h] = Wm[h * FM + k0 + lane];
    for (int r = wg; r < 16; r += 4)
      if (lane < kc) Xl[r][lane] = xm[(row0 + r) * FM + k0 + lane];
    __syncthreads();
    for (int kk = 0; kk < kc; ++kk) {
      float w = Wt[kk][lane];
#pragma unroll
      for (int j = 0; j < 4; ++j) acc[j] += Xl[wg * 4 + j][kk] * w;
    }
  }
  float b = bm[lane];
#pragma unroll
  for (int j = 0; j < 4; ++j)
    hm[(row0 + wg * 4 + j) * HD + lane] = acc[j] + b;
}

// ---------------- mean aggregation (gather over CSR) ----------------

__global__ void agg_mean_kernel(const float* __restrict__ table, const int* __restrict__ rp,
                                const int* __restrict__ csr, float* __restrict__ out, int n) {
  int wid = threadIdx.x >> 6;
  int lane = threadIdx.x & 63;
  int row = blockIdx.x * 4 + wid;
  if (row >= n) return;
  int beg = rp[row], end = rp[row + 1];
  float acc = 0.f;
  int i = beg;
  for (; i + 4 <= end; i += 4) {
    int n0 = csr[i], n1 = csr[i + 1], n2 = csr[i + 2], n3 = csr[i + 3];
    float v0 = table[n0 * HD + lane];
    float v1 = table[n1 * HD + lane];
    float v2 = table[n2 * HD + lane];
    float v3 = table[n3 * HD + lane];
    acc += v0; acc += v1; acc += v2; acc += v3;
  }
  for (; i < end; ++i) acc += table[csr[i] * HD + lane];
  float d = (float)(end - beg);
  out[row * HD + lane] = acc / fmaxf(d, 1.0f);
}

// ---------------- SAGE linear 64->64 (+bias on lin_l, optional relu) -------

__global__ void sage64_kernel(const float* __restrict__ agg, const float* __restrict__ xd,
                              const float* __restrict__ Wl, const float* __restrict__ bl,
                              const float* __restrict__ Wr, float* __restrict__ out,
                              int n, int do_relu) {
  __shared__ float WlT[HD][HD + 1];  // [k][h]
  __shared__ float WrT[HD][HD + 1];
  int t = threadIdx.x;
  int lane = t & 63, wid = t >> 6;
  for (int h = wid; h < HD; h += 4) {
    WlT[lane][h] = Wl[h * HD + lane];
    WrT[lane][h] = Wr[h * HD + lane];
  }
  __syncthreads();
  float b = bl[lane];
  int stride = gridDim.x * 4;
  for (int row = blockIdx.x * 4 + wid; row < n; row += stride) {
    float a = agg[row * HD + lane];
    float x = xd[row * HD + lane];
    float acc = b;
#pragma unroll
    for (int k = 0; k < HD; ++k) {
      float va = __shfl(a, k);
      float vx = __shfl(x, k);
      acc += va * WlT[k][lane] + vx * WrT[k][lane];
    }
    if (do_relu) acc = fmaxf(acc, 0.f);
    out[row * HD + lane] = acc;
  }
}

// ---------------- final layer 64->3 on movies ----------------

__global__ void out_kernel(const float* __restrict__ agg2, const float* __restrict__ m1,
                           const float* __restrict__ Wl2, const float* __restrict__ bl2,
                           const float* __restrict__ Wr2, float* __restrict__ out, int n) {
  int wid = threadIdx.x >> 6, lane = threadIdx.x & 63;
  int row = blockIdx.x * 4 + wid;
  if (row >= n) return;
  float a = agg2[row * HD + lane];
  float mm = m1[row * HD + lane];
#pragma unroll
  for (int g = 0; g < 3; ++g) {
    float p = a * Wl2[g * HD + lane] + mm * Wr2[g * HD + lane];
#pragma unroll
    for (int off = 32; off > 0; off >>= 1) p += __shfl_down(p, off);
    if (lane == 0) out[row * 3 + g] = p + bl2[g];
  }
}

// ---------------------------------------------------------------------------

extern "C" void kernel_launch(void* const* d_in, const int* in_sizes, int n_in,
                              void* d_out, int out_size, void* d_ws, size_t ws_size,
                              hipStream_t stream) {
  const float* x_user  = (const float*)d_in[0];
  const float* x_movie = (const float*)d_in[1];
  const int*   e_src   = (const int*)d_in[2];
  const int*   e_dst   = (const int*)d_in[3];
  const float* W_user  = (const float*)d_in[4];
  const float* b_user  = (const float*)d_in[5];
  const float* W_movie = (const float*)d_in[6];
  const float* b_movie = (const float*)d_in[7];
  const float* Wl1_um  = (const float*)d_in[8];
  const float* bl1_um  = (const float*)d_in[9];
  const float* Wr1_um  = (const float*)d_in[10];
  const float* Wl1_mu  = (const float*)d_in[11];
  const float* bl1_mu  = (const float*)d_in[12];
  const float* Wr1_mu  = (const float*)d_in[13];
  const float* Wl2_um  = (const float*)d_in[14];
  const float* bl2_um  = (const float*)d_in[15];
  const float* Wr2_um  = (const float*)d_in[16];
  float* outp = (float*)d_out;

  // workspace carve-up
  char* p = (char*)d_ws;
  size_t off = 0;
  auto take = [&](size_t bytes) { void* r = p + off; off += alignup(bytes); return r; };
  float* hu    = (float*)take(size_t(NU) * HD * 4);
  float* hm    = (float*)take(size_t(NM) * HD * 4);
  float* u1    = (float*)take(size_t(NU) * HD * 4);
  float* m1    = (float*)take(size_t(NM) * HD * 4);
  float* aggb  = (float*)take(size_t(NU) * HD * 4);   // reused for all three aggs
  int*   rp_m  = (int*)take(size_t(NM + 1) * 4);
  int*   rp_u  = (int*)take(size_t(NU + 1) * 4);
  int*   cnt_m = (int*)take(size_t(NM) * 4);
  int*   cnt_u = (int*)take(size_t(NU) * 4);
  int*   csr_m = (int*)take(size_t(NE) * 4);          // grouped by movie, stores user id
  int*   csr_u = (int*)take(size_t(NE) * 4);          // grouped by user, stores movie id
  if (off > ws_size) return;  // workspace too small -> fail validation loudly

  const int TB = 256;
  const int eblocks = (NE + TB - 1) / TB;

  // CSR build
  hipMemsetAsync(cnt_m, 0, size_t(NM) * 4, stream);
  hipMemsetAsync(cnt_u, 0, size_t(NU) * 4, stream);
  hist_kernel<<<eblocks, TB, 0, stream>>>(e_src, e_dst, cnt_u, cnt_m);
  scan_kernel<<<1, 1024, 0, stream>>>(cnt_m, rp_m, NM);
  scan_kernel<<<1, 1024, 0, stream>>>(cnt_u, rp_u, NU);
  hipMemsetAsync(cnt_m, 0, size_t(NM) * 4, stream);
  hipMemsetAsync(cnt_u, 0, size_t(NU) * 4, stream);
  fill_kernel<<<eblocks, TB, 0, stream>>>(e_src, e_dst, rp_u, rp_m, cnt_u, cnt_m, csr_u, csr_m);

  // projections
  proj_user_kernel<<<NU / 16, TB, 0, stream>>>(x_user, W_user, b_user, hu);
  proj_movie_kernel<<<NM / 16, TB, 0, stream>>>(x_movie, W_movie, b_movie, hm);

  // layer 1: movie side  m1 = relu(sage(agg(hu by dst), hm))
  agg_mean_kernel<<<(NM + 3) / 4, TB, 0, stream>>>(hu, rp_m, csr_m, aggb, NM);
  sage64_kernel<<<2048, TB, 0, stream>>>(aggb, hm, Wl1_um, bl1_um, Wr1_um, m1, NM, 1);

  // layer 1: user side  u1 = relu(sage(agg(hm by src), hu))
  agg_mean_kernel<<<(NU + 3) / 4, TB, 0, stream>>>(hm, rp_u, csr_u, aggb, NU);
  sage64_kernel<<<2048, TB, 0, stream>>>(aggb, hu, Wl1_mu, bl1_mu, Wr1_mu, u1, NU, 1);

  // layer 2: movie output
  agg_mean_kernel<<<(NM + 3) / 4, TB, 0, stream>>>(u1, rp_m, csr_m, aggb, NM);
  out_kernel<<<(NM + 3) / 4, TB, 0, stream>>>(aggb, m1, Wl2_um, bl2_um, Wr2_um, outp, NM);
}

// Round 2
// 1382.664 us; speedup vs baseline: 1.2720x; 1.2720x over previous
//
#include <hip/hip_runtime.h>

// ---------------------------------------------------------------------------
// Hetero GraphSAGE (user<->movie). Bucketed CSR build + bf16 gather tables.
// ---------------------------------------------------------------------------

constexpr int NU = 100000;   // users
constexpr int NM = 50000;    // movies
constexpr int NE = 4000000;  // edges
constexpr int FU = 24;       // user feat
constexpr int FM = 404;      // movie feat
constexpr int HD = 64;       // hidden

constexpr int BSH = 8;                       // bucket = 256 node ids
constexpr int MBK = (NM + 255) >> BSH;       // 196 movie buckets
constexpr int UBK = (NU + 255) >> BSH;       // 391 user buckets
constexpr int EPB = 8192;                    // edges per passA block (1024 thr x 8)

static inline size_t alignup(size_t x) { return (x + 255) & ~size_t(255); }

__device__ __forceinline__ float bf2f(unsigned short h) {
  return __uint_as_float(((unsigned int)h) << 16);
}
__device__ __forceinline__ unsigned short f2bf(float f) {
  unsigned int u = __float_as_uint(f);
  u = (u + 0x7FFFu + ((u >> 16) & 1u)) >> 16;   // RNE
  return (unsigned short)u;
}

// ---------------- CSR build ----------------

__global__ void hist_kernel(const int* __restrict__ src, const int* __restrict__ dst,
                            int* __restrict__ cnt_u, int* __restrict__ cnt_m) {
  int i = blockIdx.x * blockDim.x + threadIdx.x;
  if (i < NE) {
    atomicAdd(&cnt_u[src[i]], 1);
    atomicAdd(&cnt_m[dst[i]], 1);
  }
}

__global__ __launch_bounds__(1024) void scan_kernel(const int* __restrict__ cnt,
                                                    int* __restrict__ rp, int n) {
  __shared__ int lsum[1024];
  int t = threadIdx.x;
  int per = (n + 1023) >> 10;
  int beg = min(t * per, n);
  int end = min(beg + per, n);
  int s = 0;
  for (int i = beg; i < end; ++i) s += cnt[i];
  lsum[t] = s;
  __syncthreads();
  for (int off = 1; off < 1024; off <<= 1) {
    int v = (t >= off) ? lsum[t - off] : 0;
    __syncthreads();
    lsum[t] += v;
    __syncthreads();
  }
  int run = (t == 0) ? 0 : lsum[t - 1];
  for (int i = beg; i < end; ++i) { rp[i] = run; run += cnt[i]; }
  if (t == 1023) rp[n] = run;
}

__global__ void initcur_kernel(const int* __restrict__ rp_m, const int* __restrict__ rp_u,
                               int* __restrict__ bcur_m, int* __restrict__ bcur_u) {
  int t = threadIdx.x;
  if (t < MBK) bcur_m[t] = rp_m[t << BSH];
  if (t < UBK) bcur_u[t] = rp_u[t << BSH];
}

// Pass A: scatter edges into bucket-ordered staging with block-level rank
// counting (LDS) + one global range-reservation atomic per (block,bucket).
__global__ __launch_bounds__(1024) void passA_kernel(
    const int* __restrict__ src, const int* __restrict__ dst,
    int* __restrict__ bcur_m, int* __restrict__ bcur_u,
    int2* __restrict__ stage_m, int2* __restrict__ stage_u) {
  __shared__ int hB[MBK + UBK];
  int t = threadIdx.x;
  for (int i = t; i < MBK + UBK; i += 1024) hB[i] = 0;
  __syncthreads();
  int e0 = blockIdx.x * EPB + t;
  int sv[8], dv[8], rm[8], ru[8];
#pragma unroll
  for (int k = 0; k < 8; ++k) {
    int e = e0 + k * 1024;
    if (e < NE) {
      int s = src[e], d = dst[e];
      sv[k] = s; dv[k] = d;
      rm[k] = atomicAdd(&hB[d >> BSH], 1);
      ru[k] = atomicAdd(&hB[MBK + (s >> BSH)], 1);
    } else {
      sv[k] = -1;
    }
  }
  __syncthreads();
  for (int i = t; i < MBK + UBK; i += 1024) {
    int c = hB[i];
    int base = 0;
    if (c) base = (i < MBK) ? atomicAdd(&bcur_m[i], c) : atomicAdd(&bcur_u[i - MBK], c);
    hB[i] = base;
  }
  __syncthreads();
#pragma unroll
  for (int k = 0; k < 8; ++k) {
    if (sv[k] >= 0) {
      stage_m[hB[dv[k] >> BSH] + rm[k]] = make_int2(dv[k], sv[k]);
      stage_u[hB[MBK + (sv[k] >> BSH)] + ru[k]] = make_int2(sv[k], dv[k]);
    }
  }
}

// Pass B: per-bucket fine scatter. Writes land in a <=80KB L2-resident window.
__global__ __launch_bounds__(1024) void passB_kernel(
    const int* __restrict__ rp_m, const int* __restrict__ rp_u,
    const int2* __restrict__ stage_m, const int2* __restrict__ stage_u,
    int* __restrict__ csr_m, int* __restrict__ csr_u) {
  __shared__ int cur[256];
  int b = blockIdx.x;
  const int* rp; const int2* stage; int* csr; int idbase, idend;
  if (b < MBK) { rp = rp_m; stage = stage_m; csr = csr_m;
                 idbase = b << BSH; idend = min(idbase + 256, NM); }
  else { b -= MBK; rp = rp_u; stage = stage_u; csr = csr_u;
         idbase = b << BSH; idend = min(idbase + 256, NU); }
  int t = threadIdx.x;
  if (t < idend - idbase) cur[t] = rp[idbase + t];
  __syncthreads();
  int beg = rp[idbase], end = rp[idend];
  for (int j = beg + t; j < end; j += 1024) {
    int2 e = stage[j];
    int pos = atomicAdd(&cur[e.x - idbase], 1);
    csr[pos] = e.y;
  }
}

// ---------------- input projections (write bf16 tables) ----------------

__global__ void proj_user_kernel(const float* __restrict__ xu, const float* __restrict__ Wu,
                                 const float* __restrict__ bu, unsigned short* __restrict__ hu) {
  __shared__ float Wt[FU][HD + 1];
  __shared__ float Xl[16][FU];
  int t = threadIdx.x;
  int lane = t & 63, wg = t >> 6;
  int row0 = blockIdx.x * 16;
  for (int h = wg; h < HD; h += 4)
    if (lane < FU) Wt[lane][h] = Wu[h * FU + lane];
  for (int r = wg; r < 16; r += 4)
    if (lane < FU) Xl[r][lane] = xu[(row0 + r) * FU + lane];
  __syncthreads();
  float b = bu[lane];
  float acc[4] = {0.f, 0.f, 0.f, 0.f};
  for (int k = 0; k < FU; ++k) {
    float w = Wt[k][lane];
#pragma unroll
    for (int j = 0; j < 4; ++j) acc[j] += Xl[wg * 4 + j][k] * w;
  }
#pragma unroll
  for (int j = 0; j < 4; ++j)
    hu[(row0 + wg * 4 + j) * HD + lane] = f2bf(acc[j] + b);
}

__global__ void proj_movie_kernel(const float* __restrict__ xm, const float* __restrict__ Wm,
                                  const float* __restrict__ bm, unsigned short* __restrict__ hm) {
  __shared__ float Wt[64][HD + 1];
  __shared__ float Xl[16][64];
  int t = threadIdx.x;
  int lane = t & 63, wg = t >> 6;
  int row0 = blockIdx.x * 16;
  float acc[4] = {0.f, 0.f, 0.f, 0.f};
  for (int k0 = 0; k0 < FM; k0 += 64) {
    int kc = min(64, FM - k0);
    __syncthreads();
    for (int h = wg; h < HD; h += 4)
      if (lane < kc) Wt[lane][h] = Wm[h * FM + k0 + lane];
    for (int r = wg; r < 16; r += 4)
      if (lane < kc) Xl[r][lane] = xm[(row0 + r) * FM + k0 + lane];
    __syncthreads();
    for (int kk = 0; kk < kc; ++kk) {
      float w = Wt[kk][lane];
#pragma unroll
      for (int j = 0; j < 4; ++j) acc[j] += Xl[wg * 4 + j][kk] * w;
    }
  }
  float b = bm[lane];
#pragma unroll
  for (int j = 0; j < 4; ++j)
    hm[(row0 + wg * 4 + j) * HD + lane] = f2bf(acc[j] + b);
}

// ---------------- mean aggregation: gather bf16 rows, fp32 accumulate ------

__global__ void agg_mean_kernel(const unsigned short* __restrict__ table,
                                const int* __restrict__ rp, const int* __restrict__ csr,
                                float* __restrict__ out, int n) {
  int wid = threadIdx.x >> 6;
  int lane = threadIdx.x & 63;
  int row = blockIdx.x * 4 + wid;
  if (row >= n) return;
  int beg = rp[row], end = rp[row + 1];
  float acc = 0.f;
  int i = beg;
  for (; i + 4 <= end; i += 4) {
    int n0 = csr[i], n1 = csr[i + 1], n2 = csr[i + 2], n3 = csr[i + 3];
    float v0 = bf2f(table[n0 * HD + lane]);
    float v1 = bf2f(table[n1 * HD + lane]);
    float v2 = bf2f(table[n2 * HD + lane]);
    float v3 = bf2f(table[n3 * HD + lane]);
    acc += v0; acc += v1; acc += v2; acc += v3;
  }
  for (; i < end; ++i) acc += bf2f(table[csr[i] * HD + lane]);
  float d = (float)(end - beg);
  out[row * HD + lane] = acc / fmaxf(d, 1.0f);
}

// ---------------- SAGE linear 64->64 + relu ----------------

template <int OUTBF>
__global__ void sage64_kernel(const float* __restrict__ agg, const unsigned short* __restrict__ xd,
                              const float* __restrict__ Wl, const float* __restrict__ bl,
                              const float* __restrict__ Wr, void* __restrict__ outp, int n) {
  __shared__ float WlT[HD][HD + 1];
  __shared__ float WrT[HD][HD + 1];
  int t = threadIdx.x;
  int lane = t & 63, wid = t >> 6;
  for (int h = wid; h < HD; h += 4) {
    WlT[lane][h] = Wl[h * HD + lane];
    WrT[lane][h] = Wr[h * HD + lane];
  }
  __syncthreads();
  float b = bl[lane];
  int stride = gridDim.x * 4;
  for (int row = blockIdx.x * 4 + wid; row < n; row += stride) {
    float a = agg[row * HD + lane];
    float x = bf2f(xd[row * HD + lane]);
    float acc = b;
#pragma unroll
    for (int k = 0; k < HD; ++k) {
      float va = __shfl(a, k);
      float vx = __shfl(x, k);
      acc += va * WlT[k][lane] + vx * WrT[k][lane];
    }
    acc = fmaxf(acc, 0.f);
    if (OUTBF) ((unsigned short*)outp)[row * HD + lane] = f2bf(acc);
    else       ((float*)outp)[row * HD + lane] = acc;
  }
}

// ---------------- final layer 64->3 on movies ----------------

__global__ void out_kernel(const float* __restrict__ agg2, const float* __restrict__ m1,
                           const float* __restrict__ Wl2, const float* __restrict__ bl2,
                           const float* __restrict__ Wr2, float* __restrict__ out, int n) {
  int wid = threadIdx.x >> 6, lane = threadIdx.x & 63;
  int row = blockIdx.x * 4 + wid;
  if (row >= n) return;
  float a = agg2[row * HD + lane];
  float mm = m1[row * HD + lane];
#pragma unroll
  for (int g = 0; g < 3; ++g) {
    float p = a * Wl2[g * HD + lane] + mm * Wr2[g * HD + lane];
#pragma unroll
    for (int off = 32; off > 0; off >>= 1) p += __shfl_down(p, off);
    if (lane == 0) out[row * 3 + g] = p + bl2[g];
  }
}

// ---------------------------------------------------------------------------

extern "C" void kernel_launch(void* const* d_in, const int* in_sizes, int n_in,
                              void* d_out, int out_size, void* d_ws, size_t ws_size,
                              hipStream_t stream) {
  const float* x_user  = (const float*)d_in[0];
  const float* x_movie = (const float*)d_in[1];
  const int*   e_src   = (const int*)d_in[2];
  const int*   e_dst   = (const int*)d_in[3];
  const float* W_user  = (const float*)d_in[4];
  const float* b_user  = (const float*)d_in[5];
  const float* W_movie = (const float*)d_in[6];
  const float* b_movie = (const float*)d_in[7];
  const float* Wl1_um  = (const float*)d_in[8];
  const float* bl1_um  = (const float*)d_in[9];
  const float* Wr1_um  = (const float*)d_in[10];
  const float* Wl1_mu  = (const float*)d_in[11];
  const float* bl1_mu  = (const float*)d_in[12];
  const float* Wr1_mu  = (const float*)d_in[13];
  const float* Wl2_um  = (const float*)d_in[14];
  const float* bl2_um  = (const float*)d_in[15];
  const float* Wr2_um  = (const float*)d_in[16];
  float* outp = (float*)d_out;

  // ---- workspace carve-up ----
  char* p = (char*)d_ws;
  size_t off = 0;
  auto take = [&](size_t bytes) { void* r = p + off; off += alignup(bytes); return r; };

  int* rp_m   = (int*)take(size_t(NM + 1) * 4);
  int* rp_u   = (int*)take(size_t(NU + 1) * 4);
  int* cnt_m  = (int*)take(size_t(NM) * 4);
  int* cnt_u  = (int*)take(size_t(NU) * 4);
  int* bcur_m = (int*)take(size_t(MBK) * 4);
  int* bcur_u = (int*)take(size_t(UBK) * 4);
  int* csr_m  = (int*)take(size_t(NE) * 4);   // grouped by movie, stores user id
  int* csr_u  = (int*)take(size_t(NE) * 4);   // grouped by user, stores movie id

  // overlay: staging (build phase) aliases feature buffers (feature phase)
  size_t ov_base = off;
  int2* stage_m = (int2*)take(size_t(NE) * 8);
  int2* stage_u = (int2*)take(size_t(NE) * 8);
  size_t stage_end = off;
  off = ov_base;
  unsigned short* hu = (unsigned short*)take(size_t(NU) * HD * 2);
  unsigned short* hm = (unsigned short*)take(size_t(NM) * HD * 2);
  unsigned short* u1 = (unsigned short*)take(size_t(NU) * HD * 2);
  float* m1   = (float*)take(size_t(NM) * HD * 4);
  float* aggb = (float*)take(size_t(NU) * HD * 4);
  if (off < stage_end) off = stage_end;
  if (off > ws_size) return;   // workspace too small -> fail loudly

  const int TB = 256;
  const int eblocks = (NE + TB - 1) / TB;

  // ---- CSR build ----
  hipMemsetAsync(cnt_m, 0, size_t(NM) * 4, stream);
  hipMemsetAsync(cnt_u, 0, size_t(NU) * 4, stream);
  hist_kernel<<<eblocks, TB, 0, stream>>>(e_src, e_dst, cnt_u, cnt_m);
  scan_kernel<<<1, 1024, 0, stream>>>(cnt_m, rp_m, NM);
  scan_kernel<<<1, 1024, 0, stream>>>(cnt_u, rp_u, NU);
  initcur_kernel<<<1, 512, 0, stream>>>(rp_m, rp_u, bcur_m, bcur_u);
  passA_kernel<<<(NE + EPB - 1) / EPB, 1024, 0, stream>>>(e_src, e_dst, bcur_m, bcur_u,
                                                          stage_m, stage_u);
  passB_kernel<<<MBK + UBK, 1024, 0, stream>>>(rp_m, rp_u, stage_m, stage_u, csr_m, csr_u);

  // ---- projections (after build: overlay switches to feature phase) ----
  proj_user_kernel<<<NU / 16, TB, 0, stream>>>(x_user, W_user, b_user, hu);
  proj_movie_kernel<<<NM / 16, TB, 0, stream>>>(x_movie, W_movie, b_movie, hm);

  // ---- layer 1: movie side ----
  agg_mean_kernel<<<(NM + 3) / 4, TB, 0, stream>>>(hu, rp_m, csr_m, aggb, NM);
  sage64_kernel<0><<<2048, TB, 0, stream>>>(aggb, hm, Wl1_um, bl1_um, Wr1_um, m1, NM);

  // ---- layer 1: user side ----
  agg_mean_kernel<<<(NU + 3) / 4, TB, 0, stream>>>(hm, rp_u, csr_u, aggb, NU);
  sage64_kernel<1><<<2048, TB, 0, stream>>>(aggb, hu, Wl1_mu, bl1_mu, Wr1_mu, u1, NU);

  // ---- layer 2: movie output ----
  agg_mean_kernel<<<(NM + 3) / 4, TB, 0, stream>>>(u1, rp_m, csr_m, aggb, NM);
  out_kernel<<<(NM + 3) / 4, TB, 0, stream>>>(aggb, m1, Wl2_um, bl2_um, Wr2_um, outp, NM);
}

// Round 3
// 871.295 us; speedup vs baseline: 2.0185x; 1.5869x over previous
//
#include <hip/hip_runtime.h>

// ---------------------------------------------------------------------------
// Hetero GraphSAGE (user<->movie). Fully bucketed CSR build (no global
// per-node atomics), bf16 gather tables.
// ---------------------------------------------------------------------------

constexpr int NU = 100000;   // users
constexpr int NM = 50000;    // movies
constexpr int NE = 4000000;  // edges
constexpr int FU = 24;       // user feat
constexpr int FM = 404;      // movie feat
constexpr int HD = 64;       // hidden

constexpr int BSH = 8;                       // bucket = 256 node ids
constexpr int MBK = (NM + 255) >> BSH;       // 196 movie buckets
constexpr int UBK = (NU + 255) >> BSH;       // 391 user buckets
constexpr int NBK = MBK + UBK;               // 587
constexpr int EPB = 8192;                    // edges per passA block (1024 thr x 8)

static inline size_t alignup(size_t x) { return (x + 255) & ~size_t(255); }

__device__ __forceinline__ float bf2f(unsigned short h) {
  return __uint_as_float(((unsigned int)h) << 16);
}
__device__ __forceinline__ unsigned short f2bf(float f) {
  unsigned int u = __float_as_uint(f);
  u = (u + 0x7FFFu + ((u >> 16) & 1u)) >> 16;   // RNE
  return (unsigned short)u;
}

// ---------------- CSR build ----------------

// Bucket-level histogram: LDS bins, one global atomic per (block, bin).
__global__ __launch_bounds__(256) void histB_kernel(const int* __restrict__ src,
                                                    const int* __restrict__ dst,
                                                    int* __restrict__ bh) {
  __shared__ int h[NBK];
  for (int i = threadIdx.x; i < NBK; i += 256) h[i] = 0;
  __syncthreads();
  int idx = blockIdx.x * 256 + threadIdx.x;
  int stride = gridDim.x * 256;
  for (int i = idx; i < NE; i += stride) {
    atomicAdd(&h[dst[i] >> BSH], 1);
    atomicAdd(&h[MBK + (src[i] >> BSH)], 1);
  }
  __syncthreads();
  for (int i = threadIdx.x; i < NBK; i += 256) {
    int c = h[i];
    if (c) atomicAdd(&bh[i], c);
  }
}

// Scan 587 bucket counts -> bucket base offsets (+ cursor copies for passA).
__global__ __launch_bounds__(1024) void scanB_kernel(const int* __restrict__ bh,
                                                     int* __restrict__ bbase_m,
                                                     int* __restrict__ bbase_u,
                                                     int* __restrict__ bcur_m,
                                                     int* __restrict__ bcur_u) {
  __shared__ int tmp[1024];
  int t = threadIdx.x;
  int vm = (t < MBK) ? bh[t] : 0;
  tmp[t] = vm;
  __syncthreads();
  for (int off = 1; off < 1024; off <<= 1) {
    int v = (t >= off) ? tmp[t - off] : 0;
    __syncthreads();
    tmp[t] += v;
    __syncthreads();
  }
  if (t < MBK) {
    int e = tmp[t] - vm;
    bbase_m[t] = e; bcur_m[t] = e;
    if (t == MBK - 1) bbase_m[MBK] = tmp[t];
  }
  __syncthreads();
  int vu = (t < UBK) ? bh[MBK + t] : 0;
  tmp[t] = vu;
  __syncthreads();
  for (int off = 1; off < 1024; off <<= 1) {
    int v = (t >= off) ? tmp[t - off] : 0;
    __syncthreads();
    tmp[t] += v;
    __syncthreads();
  }
  if (t < UBK) {
    int e = tmp[t] - vu;
    bbase_u[t] = e; bcur_u[t] = e;
    if (t == UBK - 1) bbase_u[UBK] = tmp[t];
  }
}

// Pass A: scatter edges into bucket-ordered staging with block-level rank
// counting (LDS) + one global range-reservation atomic per (block,bucket).
// Staged entry: (local_node_id << 24) | payload_node_id  (payload < 2^17).
__global__ __launch_bounds__(1024) void passA_kernel(
    const int* __restrict__ src, const int* __restrict__ dst,
    int* __restrict__ bcur_m, int* __restrict__ bcur_u,
    unsigned* __restrict__ stage_m, unsigned* __restrict__ stage_u) {
  __shared__ int hB[NBK];
  int t = threadIdx.x;
  for (int i = t; i < NBK; i += 1024) hB[i] = 0;
  __syncthreads();
  int e0 = blockIdx.x * EPB + t;
  int sv[8], dv[8], rm[8], ru[8];
#pragma unroll
  for (int k = 0; k < 8; ++k) {
    int e = e0 + k * 1024;
    if (e < NE) {
      int s = src[e], d = dst[e];
      sv[k] = s; dv[k] = d;
      rm[k] = atomicAdd(&hB[d >> BSH], 1);
      ru[k] = atomicAdd(&hB[MBK + (s >> BSH)], 1);
    } else {
      sv[k] = -1;
    }
  }
  __syncthreads();
  for (int i = t; i < NBK; i += 1024) {
    int c = hB[i];
    int base = 0;
    if (c) base = (i < MBK) ? atomicAdd(&bcur_m[i], c) : atomicAdd(&bcur_u[i - MBK], c);
    hB[i] = base;
  }
  __syncthreads();
#pragma unroll
  for (int k = 0; k < 8; ++k) {
    if (sv[k] >= 0) {
      int s = sv[k], d = dv[k];
      stage_m[hB[d >> BSH] + rm[k]] = ((unsigned)(d & 255) << 24) | (unsigned)s;
      stage_u[hB[MBK + (s >> BSH)] + ru[k]] = ((unsigned)(s & 255) << 24) | (unsigned)d;
    }
  }
}

// Pass B: per-bucket. Count per-node in LDS, LDS-scan -> write rp, then
// fine-scatter payloads into the bucket's CSR window (L2-resident).
__global__ __launch_bounds__(1024) void passB_kernel(
    const int* __restrict__ bbase_m, const int* __restrict__ bbase_u,
    const unsigned* __restrict__ stage_m, const unsigned* __restrict__ stage_u,
    int* __restrict__ csr_m, int* __restrict__ csr_u,
    int* __restrict__ rp_m, int* __restrict__ rp_u) {
  __shared__ int cnt[256];
  __shared__ int sc[256];
  int b = blockIdx.x;
  const unsigned* stage; int* csr; int* rp; int idbase, ntot, bb, be;
  if (b < MBK) {
    stage = stage_m; csr = csr_m; rp = rp_m;
    idbase = b << BSH; ntot = NM;
    bb = bbase_m[b]; be = bbase_m[b + 1];
  } else {
    int c = b - MBK;
    stage = stage_u; csr = csr_u; rp = rp_u;
    idbase = c << BSH; ntot = NU;
    bb = bbase_u[c]; be = bbase_u[c + 1];
  }
  int nloc = min(256, ntot - idbase);
  int t = threadIdx.x;
  if (t < 256) cnt[t] = 0;
  __syncthreads();
  for (int j = bb + t; j < be; j += 1024) atomicAdd(&cnt[stage[j] >> 24], 1);
  __syncthreads();
  int c0 = (t < 256) ? cnt[t] : 0;
  if (t < 256) sc[t] = c0;
  __syncthreads();
  for (int off = 1; off < 256; off <<= 1) {
    int v = 0;
    if (t < 256 && t >= off) v = sc[t - off];
    __syncthreads();
    if (t < 256) sc[t] += v;
    __syncthreads();
  }
  if (t < nloc) {
    int e = bb + sc[t] - c0;        // global CSR offset for node idbase+t
    rp[idbase + t] = e;
    cnt[t] = e;                     // reuse as cursor
  }
  if (t == 0 && idbase + nloc == ntot) rp[ntot] = be;
  __syncthreads();
  for (int j = bb + t; j < be; j += 1024) {
    unsigned e = stage[j];
    int pos = atomicAdd(&cnt[e >> 24], 1);
    csr[pos] = (int)(e & 0xFFFFFFu);
  }
}

// ---------------- input projections (write bf16 tables) ----------------

__global__ void proj_user_kernel(const float* __restrict__ xu, const float* __restrict__ Wu,
                                 const float* __restrict__ bu, unsigned short* __restrict__ hu) {
  __shared__ float Wt[FU][HD + 1];
  __shared__ float Xl[16][FU];
  int t = threadIdx.x;
  int lane = t & 63, wg = t >> 6;
  int row0 = blockIdx.x * 16;
  for (int h = wg; h < HD; h += 4)
    if (lane < FU) Wt[lane][h] = Wu[h * FU + lane];
  for (int r = wg; r < 16; r += 4)
    if (lane < FU) Xl[r][lane] = xu[(row0 + r) * FU + lane];
  __syncthreads();
  float b = bu[lane];
  float acc[4] = {0.f, 0.f, 0.f, 0.f};
  for (int k = 0; k < FU; ++k) {
    float w = Wt[k][lane];
#pragma unroll
    for (int j = 0; j < 4; ++j) acc[j] += Xl[wg * 4 + j][k] * w;
  }
#pragma unroll
  for (int j = 0; j < 4; ++j)
    hu[(row0 + wg * 4 + j) * HD + lane] = f2bf(acc[j] + b);
}

__global__ void proj_movie_kernel(const float* __restrict__ xm, const float* __restrict__ Wm,
                                  const float* __restrict__ bm, unsigned short* __restrict__ hm) {
  __shared__ float Wt[64][HD + 1];
  __shared__ float Xl[16][64];
  int t = threadIdx.x;
  int lane = t & 63, wg = t >> 6;
  int row0 = blockIdx.x * 16;
  float acc[4] = {0.f, 0.f, 0.f, 0.f};
  for (int k0 = 0; k0 < FM; k0 += 64) {
    int kc = min(64, FM - k0);
    __syncthreads();
    for (int h = wg; h < HD; h += 4)
      if (lane < kc) Wt[lane][h] = Wm[h * FM + k0 + lane];
    for (int r = wg; r < 16; r += 4)
      if (lane < kc) Xl[r][lane] = xm[(row0 + r) * FM + k0 + lane];
    __syncthreads();
    for (int kk = 0; kk < kc; ++kk) {
      float w = Wt[kk][lane];
#pragma unroll
      for (int j = 0; j < 4; ++j) acc[j] += Xl[wg * 4 + j][kk] * w;
    }
  }
  float b = bm[lane];
#pragma unroll
  for (int j = 0; j < 4; ++j)
    hm[(row0 + wg * 4 + j) * HD + lane] = f2bf(acc[j] + b);
}

// ---------------- mean aggregation: gather bf16 rows, fp32 accumulate ------

__global__ void agg_mean_kernel(const unsigned short* __restrict__ table,
                                const int* __restrict__ rp, const int* __restrict__ csr,
                                float* __restrict__ out, int n) {
  int wid = threadIdx.x >> 6;
  int lane = threadIdx.x & 63;
  int row = blockIdx.x * 4 + wid;
  if (row >= n) return;
  int beg = rp[row], end = rp[row + 1];
  float acc = 0.f;
  int i = beg;
  for (; i + 4 <= end; i += 4) {
    int n0 = csr[i], n1 = csr[i + 1], n2 = csr[i + 2], n3 = csr[i + 3];
    float v0 = bf2f(table[n0 * HD + lane]);
    float v1 = bf2f(table[n1 * HD + lane]);
    float v2 = bf2f(table[n2 * HD + lane]);
    float v3 = bf2f(table[n3 * HD + lane]);
    acc += v0; acc += v1; acc += v2; acc += v3;
  }
  for (; i < end; ++i) acc += bf2f(table[csr[i] * HD + lane]);
  float d = (float)(end - beg);
  out[row * HD + lane] = acc / fmaxf(d, 1.0f);
}

// ---------------- SAGE linear 64->64 + relu ----------------

template <int OUTBF>
__global__ void sage64_kernel(const float* __restrict__ agg, const unsigned short* __restrict__ xd,
                              const float* __restrict__ Wl, const float* __restrict__ bl,
                              const float* __restrict__ Wr, void* __restrict__ outp, int n) {
  __shared__ float WlT[HD][HD + 1];
  __shared__ float WrT[HD][HD + 1];
  int t = threadIdx.x;
  int lane = t & 63, wid = t >> 6;
  for (int h = wid; h < HD; h += 4) {
    WlT[lane][h] = Wl[h * HD + lane];
    WrT[lane][h] = Wr[h * HD + lane];
  }
  __syncthreads();
  float b = bl[lane];
  int stride = gridDim.x * 4;
  for (int row = blockIdx.x * 4 + wid; row < n; row += stride) {
    float a = agg[row * HD + lane];
    float x = bf2f(xd[row * HD + lane]);
    float acc = b;
#pragma unroll
    for (int k = 0; k < HD; ++k) {
      float va = __shfl(a, k);
      float vx = __shfl(x, k);
      acc += va * WlT[k][lane] + vx * WrT[k][lane];
    }
    acc = fmaxf(acc, 0.f);
    if (OUTBF) ((unsigned short*)outp)[row * HD + lane] = f2bf(acc);
    else       ((float*)outp)[row * HD + lane] = acc;
  }
}

// ---------------- final layer 64->3 on movies ----------------

__global__ void out_kernel(const float* __restrict__ agg2, const float* __restrict__ m1,
                           const float* __restrict__ Wl2, const float* __restrict__ bl2,
                           const float* __restrict__ Wr2, float* __restrict__ out, int n) {
  int wid = threadIdx.x >> 6, lane = threadIdx.x & 63;
  int row = blockIdx.x * 4 + wid;
  if (row >= n) return;
  float a = agg2[row * HD + lane];
  float mm = m1[row * HD + lane];
#pragma unroll
  for (int g = 0; g < 3; ++g) {
    float p = a * Wl2[g * HD + lane] + mm * Wr2[g * HD + lane];
#pragma unroll
    for (int off = 32; off > 0; off >>= 1) p += __shfl_down(p, off);
    if (lane == 0) out[row * 3 + g] = p + bl2[g];
  }
}

// ---------------------------------------------------------------------------

extern "C" void kernel_launch(void* const* d_in, const int* in_sizes, int n_in,
                              void* d_out, int out_size, void* d_ws, size_t ws_size,
                              hipStream_t stream) {
  const float* x_user  = (const float*)d_in[0];
  const float* x_movie = (const float*)d_in[1];
  const int*   e_src   = (const int*)d_in[2];
  const int*   e_dst   = (const int*)d_in[3];
  const float* W_user  = (const float*)d_in[4];
  const float* b_user  = (const float*)d_in[5];
  const float* W_movie = (const float*)d_in[6];
  const float* b_movie = (const float*)d_in[7];
  const float* Wl1_um  = (const float*)d_in[8];
  const float* bl1_um  = (const float*)d_in[9];
  const float* Wr1_um  = (const float*)d_in[10];
  const float* Wl1_mu  = (const float*)d_in[11];
  const float* bl1_mu  = (const float*)d_in[12];
  const float* Wr1_mu  = (const float*)d_in[13];
  const float* Wl2_um  = (const float*)d_in[14];
  const float* bl2_um  = (const float*)d_in[15];
  const float* Wr2_um  = (const float*)d_in[16];
  float* outp = (float*)d_out;

  // ---- workspace carve-up ----
  char* p = (char*)d_ws;
  size_t off = 0;
  auto take = [&](size_t bytes) { void* r = p + off; off += alignup(bytes); return r; };

  int* rp_m    = (int*)take(size_t(NM + 1) * 4);
  int* rp_u    = (int*)take(size_t(NU + 1) * 4);
  int* bh      = (int*)take(size_t(NBK) * 4);
  int* bbase_m = (int*)take(size_t(MBK + 1) * 4);
  int* bbase_u = (int*)take(size_t(UBK + 1) * 4);
  int* bcur_m  = (int*)take(size_t(MBK) * 4);
  int* bcur_u  = (int*)take(size_t(UBK) * 4);
  int* csr_m   = (int*)take(size_t(NE) * 4);   // grouped by movie, stores user id
  int* csr_u   = (int*)take(size_t(NE) * 4);   // grouped by user, stores movie id

  // overlay: staging (build phase) aliases feature buffers (feature phase)
  size_t ov_base = off;
  unsigned* stage_m = (unsigned*)take(size_t(NE) * 4);
  unsigned* stage_u = (unsigned*)take(size_t(NE) * 4);
  size_t stage_end = off;
  off = ov_base;
  unsigned short* hu = (unsigned short*)take(size_t(NU) * HD * 2);
  unsigned short* hm = (unsigned short*)take(size_t(NM) * HD * 2);
  unsigned short* u1 = (unsigned short*)take(size_t(NU) * HD * 2);
  float* m1   = (float*)take(size_t(NM) * HD * 4);
  float* aggb = (float*)take(size_t(NU) * HD * 4);
  if (off < stage_end) off = stage_end;
  if (off > ws_size) return;   // workspace too small -> fail loudly

  const int TB = 256;

  // ---- CSR build (bucketed; no global per-node atomics) ----
  hipMemsetAsync(bh, 0, size_t(NBK) * 4, stream);
  histB_kernel<<<512, 256, 0, stream>>>(e_src, e_dst, bh);
  scanB_kernel<<<1, 1024, 0, stream>>>(bh, bbase_m, bbase_u, bcur_m, bcur_u);
  passA_kernel<<<(NE + EPB - 1) / EPB, 1024, 0, stream>>>(e_src, e_dst, bcur_m, bcur_u,
                                                          stage_m, stage_u);
  passB_kernel<<<NBK, 1024, 0, stream>>>(bbase_m, bbase_u, stage_m, stage_u,
                                         csr_m, csr_u, rp_m, rp_u);

  // ---- projections (after build: overlay switches to feature phase) ----
  proj_user_kernel<<<NU / 16, TB, 0, stream>>>(x_user, W_user, b_user, hu);
  proj_movie_kernel<<<NM / 16, TB, 0, stream>>>(x_movie, W_movie, b_movie, hm);

  // ---- layer 1: movie side ----
  agg_mean_kernel<<<(NM + 3) / 4, TB, 0, stream>>>(hu, rp_m, csr_m, aggb, NM);
  sage64_kernel<0><<<2048, TB, 0, stream>>>(aggb, hm, Wl1_um, bl1_um, Wr1_um, m1, NM);

  // ---- layer 1: user side ----
  agg_mean_kernel<<<(NU + 3) / 4, TB, 0, stream>>>(hm, rp_u, csr_u, aggb, NU);
  sage64_kernel<1><<<2048, TB, 0, stream>>>(aggb, hu, Wl1_mu, bl1_mu, Wr1_mu, u1, NU);

  // ---- layer 2: movie output ----
  agg_mean_kernel<<<(NM + 3) / 4, TB, 0, stream>>>(u1, rp_m, csr_m, aggb, NM);
  out_kernel<<<(NM + 3) / 4, TB, 0, stream>>>(aggb, m1, Wl2_um, bl2_um, Wr2_um, outp, NM);
}

// Round 4
// 594.662 us; speedup vs baseline: 2.9575x; 1.4652x over previous
//
#include <hip/hip_runtime.h>

// ---------------------------------------------------------------------------
// Hetero GraphSAGE (user<->movie). Bucketed CSR build, bf16 gather tables,
// register-tiled SAGE linear.
// ---------------------------------------------------------------------------

constexpr int NU = 100000;   // users
constexpr int NM = 50000;    // movies
constexpr int NE = 4000000;  // edges
constexpr int FU = 24;       // user feat
constexpr int FM = 404;      // movie feat
constexpr int HD = 64;       // hidden

constexpr int BSH = 8;                       // bucket = 256 node ids
constexpr int MBK = (NM + 255) >> BSH;       // 196 movie buckets
constexpr int UBK = (NU + 255) >> BSH;       // 391 user buckets
constexpr int NBK = MBK + UBK;               // 587
constexpr int EPB = 8192;                    // edges per passA block (1024 thr x 8)

static inline size_t alignup(size_t x) { return (x + 255) & ~size_t(255); }

__device__ __forceinline__ float bf2f(unsigned short h) {
  return __uint_as_float(((unsigned int)h) << 16);
}
__device__ __forceinline__ unsigned short f2bf(float f) {
  unsigned int u = __float_as_uint(f);
  u = (u + 0x7FFFu + ((u >> 16) & 1u)) >> 16;   // RNE
  return (unsigned short)u;
}
__device__ __forceinline__ float2 unpk(unsigned u) {
  return make_float2(__uint_as_float(u << 16), __uint_as_float(u & 0xFFFF0000u));
}

// ---------------- CSR build ----------------

__global__ __launch_bounds__(256) void histB_kernel(const int* __restrict__ src,
                                                    const int* __restrict__ dst,
                                                    int* __restrict__ bh) {
  __shared__ int h[NBK];
  for (int i = threadIdx.x; i < NBK; i += 256) h[i] = 0;
  __syncthreads();
  int idx = blockIdx.x * 256 + threadIdx.x;
  int stride = gridDim.x * 256;
  for (int i = idx; i < NE; i += stride) {
    atomicAdd(&h[dst[i] >> BSH], 1);
    atomicAdd(&h[MBK + (src[i] >> BSH)], 1);
  }
  __syncthreads();
  for (int i = threadIdx.x; i < NBK; i += 256) {
    int c = h[i];
    if (c) atomicAdd(&bh[i], c);
  }
}

__global__ __launch_bounds__(1024) void scanB_kernel(const int* __restrict__ bh,
                                                     int* __restrict__ bbase_m,
                                                     int* __restrict__ bbase_u,
                                                     int* __restrict__ bcur_m,
                                                     int* __restrict__ bcur_u) {
  __shared__ int tmp[1024];
  int t = threadIdx.x;
  int vm = (t < MBK) ? bh[t] : 0;
  tmp[t] = vm;
  __syncthreads();
  for (int off = 1; off < 1024; off <<= 1) {
    int v = (t >= off) ? tmp[t - off] : 0;
    __syncthreads();
    tmp[t] += v;
    __syncthreads();
  }
  if (t < MBK) {
    int e = tmp[t] - vm;
    bbase_m[t] = e; bcur_m[t] = e;
    if (t == MBK - 1) bbase_m[MBK] = tmp[t];
  }
  __syncthreads();
  int vu = (t < UBK) ? bh[MBK + t] : 0;
  tmp[t] = vu;
  __syncthreads();
  for (int off = 1; off < 1024; off <<= 1) {
    int v = (t >= off) ? tmp[t - off] : 0;
    __syncthreads();
    tmp[t] += v;
    __syncthreads();
  }
  if (t < UBK) {
    int e = tmp[t] - vu;
    bbase_u[t] = e; bcur_u[t] = e;
    if (t == UBK - 1) bbase_u[UBK] = tmp[t];
  }
}

// Pass A: scatter edges into bucket-ordered staging.
// Staged entry: (local_node_id << 24) | payload_node_id (payload < 2^17).
__global__ __launch_bounds__(1024) void passA_kernel(
    const int* __restrict__ src, const int* __restrict__ dst,
    int* __restrict__ bcur_m, int* __restrict__ bcur_u,
    unsigned* __restrict__ stage_m, unsigned* __restrict__ stage_u) {
  __shared__ int hB[NBK];
  int t = threadIdx.x;
  for (int i = t; i < NBK; i += 1024) hB[i] = 0;
  __syncthreads();
  int e0 = blockIdx.x * EPB + t;
  int sv[8], dv[8], rm[8], ru[8];
#pragma unroll
  for (int k = 0; k < 8; ++k) {
    int e = e0 + k * 1024;
    if (e < NE) {
      int s = src[e], d = dst[e];
      sv[k] = s; dv[k] = d;
      rm[k] = atomicAdd(&hB[d >> BSH], 1);
      ru[k] = atomicAdd(&hB[MBK + (s >> BSH)], 1);
    } else {
      sv[k] = -1;
    }
  }
  __syncthreads();
  for (int i = t; i < NBK; i += 1024) {
    int c = hB[i];
    int base = 0;
    if (c) base = (i < MBK) ? atomicAdd(&bcur_m[i], c) : atomicAdd(&bcur_u[i - MBK], c);
    hB[i] = base;
  }
  __syncthreads();
#pragma unroll
  for (int k = 0; k < 8; ++k) {
    if (sv[k] >= 0) {
      int s = sv[k], d = dv[k];
      stage_m[hB[d >> BSH] + rm[k]] = ((unsigned)(d & 255) << 24) | (unsigned)s;
      stage_u[hB[MBK + (s >> BSH)] + ru[k]] = ((unsigned)(s & 255) << 24) | (unsigned)d;
    }
  }
}

// Pass B: per-bucket count + LDS scan -> rp, then fine scatter into CSR.
__global__ __launch_bounds__(1024) void passB_kernel(
    const int* __restrict__ bbase_m, const int* __restrict__ bbase_u,
    const unsigned* __restrict__ stage_m, const unsigned* __restrict__ stage_u,
    int* __restrict__ csr_m, int* __restrict__ csr_u,
    int* __restrict__ rp_m, int* __restrict__ rp_u) {
  __shared__ int cnt[256];
  __shared__ int sc[256];
  int b = blockIdx.x;
  const unsigned* stage; int* csr; int* rp; int idbase, ntot, bb, be;
  if (b < MBK) {
    stage = stage_m; csr = csr_m; rp = rp_m;
    idbase = b << BSH; ntot = NM;
    bb = bbase_m[b]; be = bbase_m[b + 1];
  } else {
    int c = b - MBK;
    stage = stage_u; csr = csr_u; rp = rp_u;
    idbase = c << BSH; ntot = NU;
    bb = bbase_u[c]; be = bbase_u[c + 1];
  }
  int nloc = min(256, ntot - idbase);
  int t = threadIdx.x;
  if (t < 256) cnt[t] = 0;
  __syncthreads();
  for (int j = bb + t; j < be; j += 1024) atomicAdd(&cnt[stage[j] >> 24], 1);
  __syncthreads();
  int c0 = (t < 256) ? cnt[t] : 0;
  if (t < 256) sc[t] = c0;
  __syncthreads();
  for (int off = 1; off < 256; off <<= 1) {
    int v = 0;
    if (t < 256 && t >= off) v = sc[t - off];
    __syncthreads();
    if (t < 256) sc[t] += v;
    __syncthreads();
  }
  if (t < nloc) {
    int e = bb + sc[t] - c0;
    rp[idbase + t] = e;
    cnt[t] = e;                     // reuse as cursor
  }
  if (t == 0 && idbase + nloc == ntot) rp[ntot] = be;
  __syncthreads();
  for (int j = bb + t; j < be; j += 1024) {
    unsigned e = stage[j];
    int pos = atomicAdd(&cnt[e >> 24], 1);
    csr[pos] = (int)(e & 0xFFFFFFu);
  }
}

// ---------------- input projections (write bf16 tables) ----------------

__global__ void proj_user_kernel(const float* __restrict__ xu, const float* __restrict__ Wu,
                                 const float* __restrict__ bu, unsigned short* __restrict__ hu) {
  __shared__ float Wt[FU][HD + 1];
  __shared__ float Xl[16][FU];
  int t = threadIdx.x;
  int lane = t & 63, wg = t >> 6;
  int row0 = blockIdx.x * 16;
  for (int h = wg; h < HD; h += 4)
    if (lane < FU) Wt[lane][h] = Wu[h * FU + lane];
  for (int r = wg; r < 16; r += 4)
    if (lane < FU) Xl[r][lane] = xu[(row0 + r) * FU + lane];
  __syncthreads();
  float b = bu[lane];
  float acc[4] = {0.f, 0.f, 0.f, 0.f};
  for (int k = 0; k < FU; ++k) {
    float w = Wt[k][lane];
#pragma unroll
    for (int j = 0; j < 4; ++j) acc[j] += Xl[wg * 4 + j][k] * w;
  }
#pragma unroll
  for (int j = 0; j < 4; ++j)
    hu[(row0 + wg * 4 + j) * HD + lane] = f2bf(acc[j] + b);
}

__global__ void proj_movie_kernel(const float* __restrict__ xm, const float* __restrict__ Wm,
                                  const float* __restrict__ bm, unsigned short* __restrict__ hm) {
  __shared__ float Wt[64][HD + 1];
  __shared__ float Xl[16][64];
  int t = threadIdx.x;
  int lane = t & 63, wg = t >> 6;
  int row0 = blockIdx.x * 16;
  float acc[4] = {0.f, 0.f, 0.f, 0.f};
  for (int k0 = 0; k0 < FM; k0 += 64) {
    int kc = min(64, FM - k0);
    __syncthreads();
    for (int h = wg; h < HD; h += 4)
      if (lane < kc) Wt[lane][h] = Wm[h * FM + k0 + lane];
    for (int r = wg; r < 16; r += 4)
      if (lane < kc) Xl[r][lane] = xm[(row0 + r) * FM + k0 + lane];
    __syncthreads();
    for (int kk = 0; kk < kc; ++kk) {
      float w = Wt[kk][lane];
#pragma unroll
      for (int j = 0; j < 4; ++j) acc[j] += Xl[wg * 4 + j][kk] * w;
    }
  }
  float b = bm[lane];
#pragma unroll
  for (int j = 0; j < 4; ++j)
    hm[(row0 + wg * 4 + j) * HD + lane] = f2bf(acc[j] + b);
}

// ---------------- mean aggregation: 4 neighbors/wave, 8B/lane gathers ------

__global__ __launch_bounds__(256) void agg_mean_kernel(
    const unsigned short* __restrict__ table, const int* __restrict__ rp,
    const int* __restrict__ csr, float* __restrict__ out, int n) {
  int wid = threadIdx.x >> 6;
  int lane = threadIdx.x & 63;
  int row = blockIdx.x * 4 + wid;
  if (row >= n) return;
  int beg = rp[row], end = rp[row + 1];
  int g = lane >> 4;        // neighbor slot 0..3
  int fq = lane & 15;       // feature quad
  float a0 = 0.f, a1 = 0.f, a2 = 0.f, a3 = 0.f;
  int i = beg;
  for (; i + 8 <= end; i += 8) {
    int n0 = csr[i + g];
    int n1 = csr[i + 4 + g];
    uint2 v0 = *(const uint2*)(table + (size_t)n0 * HD + fq * 4);
    uint2 v1 = *(const uint2*)(table + (size_t)n1 * HD + fq * 4);
    float2 p0 = unpk(v0.x), p1 = unpk(v0.y);
    float2 q0 = unpk(v1.x), q1 = unpk(v1.y);
    a0 += p0.x + q0.x; a1 += p0.y + q0.y;
    a2 += p1.x + q1.x; a3 += p1.y + q1.y;
  }
  for (; i < end; i += 4) {
    int idx = i + g;
    if (idx < end) {
      int nb = csr[idx];
      uint2 v = *(const uint2*)(table + (size_t)nb * HD + fq * 4);
      float2 p0 = unpk(v.x), p1 = unpk(v.y);
      a0 += p0.x; a1 += p0.y; a2 += p1.x; a3 += p1.y;
    }
  }
  a0 += __shfl_xor(a0, 16); a0 += __shfl_xor(a0, 32);
  a1 += __shfl_xor(a1, 16); a1 += __shfl_xor(a1, 32);
  a2 += __shfl_xor(a2, 16); a2 += __shfl_xor(a2, 32);
  a3 += __shfl_xor(a3, 16); a3 += __shfl_xor(a3, 32);
  float inv = 1.0f / fmaxf((float)(end - beg), 1.0f);
  if (lane < 16) {
    float4 o = make_float4(a0 * inv, a1 * inv, a2 * inv, a3 * inv);
    *(float4*)(out + (size_t)row * HD + fq * 4) = o;
  }
}

// ---------------- SAGE linear 64->64 + relu (register-tiled) ----------------
// out[r,h] = relu( sum_k cat(agg[r],x[r])[k] * Ws[k][h] + bl[h] )

template <int OUTBF>
__global__ __launch_bounds__(256, 3) void sage64_kernel(
    const float* __restrict__ agg, const unsigned short* __restrict__ xd,
    const float* __restrict__ Wl, const float* __restrict__ bl,
    const float* __restrict__ Wr, void* __restrict__ outp, int n) {
  __shared__ float Ws[128][65];     // [k][h], padded (transpose-write safe)
  __shared__ float Xs[32][128];     // [row][k] : k<64 agg, k>=64 x
  int t = threadIdx.x;
  int lane = t & 63, wid = t >> 6;
  int row0 = blockIdx.x * 32;
  // stage W (coalesced read, conflict-free transpose write)
  for (int i = t; i < 4096; i += 256) {
    int h = i >> 6, k = i & 63;
    Ws[k][h] = Wl[i];
  }
  for (int i = t; i < 4096; i += 256) {
    int h = i >> 6, k = i & 63;
    Ws[64 + k][h] = Wr[i];
  }
  // stage X tile: agg rows (fp32) and x rows (bf16 -> f32)
  for (int i = t; i < 512; i += 256) {
    int r = i >> 4, c4 = i & 15;
    if (row0 + r < n) {
      float4 v = ((const float4*)(agg + (size_t)(row0 + r) * HD))[c4];
      *(float4*)&Xs[r][c4 * 4] = v;
    }
  }
  for (int i = t; i < 512; i += 256) {
    int r = i >> 4, c4 = i & 15;
    if (row0 + r < n) {
      uint2 v = ((const uint2*)(xd + (size_t)(row0 + r) * HD))[c4];
      float2 p0 = unpk(v.x), p1 = unpk(v.y);
      *(float4*)&Xs[r][64 + c4 * 4] = make_float4(p0.x, p0.y, p1.x, p1.y);
    }
  }
  __syncthreads();
  float acc[8] = {0.f, 0.f, 0.f, 0.f, 0.f, 0.f, 0.f, 0.f};
  int rbase = wid * 8;
#pragma unroll 4
  for (int k = 0; k < 128; ++k) {
    float wv = Ws[k][lane];
#pragma unroll
    for (int j = 0; j < 8; ++j) acc[j] += Xs[rbase + j][k] * wv;
  }
  float b = bl[lane];
#pragma unroll
  for (int j = 0; j < 8; ++j) {
    int row = row0 + rbase + j;
    if (row < n) {
      float v = fmaxf(acc[j] + b, 0.f);
      if (OUTBF) ((unsigned short*)outp)[(size_t)row * HD + lane] = f2bf(v);
      else       ((float*)outp)[(size_t)row * HD + lane] = v;
    }
  }
}

// ---------------- final layer 64->3 on movies ----------------

__global__ void out_kernel(const float* __restrict__ agg2, const float* __restrict__ m1,
                           const float* __restrict__ Wl2, const float* __restrict__ bl2,
                           const float* __restrict__ Wr2, float* __restrict__ out, int n) {
  int wid = threadIdx.x >> 6, lane = threadIdx.x & 63;
  int row = blockIdx.x * 4 + wid;
  if (row >= n) return;
  float a = agg2[row * HD + lane];
  float mm = m1[row * HD + lane];
#pragma unroll
  for (int g = 0; g < 3; ++g) {
    float p = a * Wl2[g * HD + lane] + mm * Wr2[g * HD + lane];
#pragma unroll
    for (int off = 32; off > 0; off >>= 1) p += __shfl_down(p, off);
    if (lane == 0) out[row * 3 + g] = p + bl2[g];
  }
}

// ---------------------------------------------------------------------------

extern "C" void kernel_launch(void* const* d_in, const int* in_sizes, int n_in,
                              void* d_out, int out_size, void* d_ws, size_t ws_size,
                              hipStream_t stream) {
  const float* x_user  = (const float*)d_in[0];
  const float* x_movie = (const float*)d_in[1];
  const int*   e_src   = (const int*)d_in[2];
  const int*   e_dst   = (const int*)d_in[3];
  const float* W_user  = (const float*)d_in[4];
  const float* b_user  = (const float*)d_in[5];
  const float* W_movie = (const float*)d_in[6];
  const float* b_movie = (const float*)d_in[7];
  const float* Wl1_um  = (const float*)d_in[8];
  const float* bl1_um  = (const float*)d_in[9];
  const float* Wr1_um  = (const float*)d_in[10];
  const float* Wl1_mu  = (const float*)d_in[11];
  const float* bl1_mu  = (const float*)d_in[12];
  const float* Wr1_mu  = (const float*)d_in[13];
  const float* Wl2_um  = (const float*)d_in[14];
  const float* bl2_um  = (const float*)d_in[15];
  const float* Wr2_um  = (const float*)d_in[16];
  float* outp = (float*)d_out;

  // ---- workspace carve-up ----
  char* p = (char*)d_ws;
  size_t off = 0;
  auto take = [&](size_t bytes) { void* r = p + off; off += alignup(bytes); return r; };

  int* rp_m    = (int*)take(size_t(NM + 1) * 4);
  int* rp_u    = (int*)take(size_t(NU + 1) * 4);
  int* bh      = (int*)take(size_t(NBK) * 4);
  int* bbase_m = (int*)take(size_t(MBK + 1) * 4);
  int* bbase_u = (int*)take(size_t(UBK + 1) * 4);
  int* bcur_m  = (int*)take(size_t(MBK) * 4);
  int* bcur_u  = (int*)take(size_t(UBK) * 4);
  int* csr_m   = (int*)take(size_t(NE) * 4);   // grouped by movie, stores user id
  int* csr_u   = (int*)take(size_t(NE) * 4);   // grouped by user, stores movie id

  // overlay: staging (build phase) aliases feature buffers (feature phase)
  size_t ov_base = off;
  unsigned* stage_m = (unsigned*)take(size_t(NE) * 4);
  unsigned* stage_u = (unsigned*)take(size_t(NE) * 4);
  size_t stage_end = off;
  off = ov_base;
  unsigned short* hu = (unsigned short*)take(size_t(NU) * HD * 2);
  unsigned short* hm = (unsigned short*)take(size_t(NM) * HD * 2);
  unsigned short* u1 = (unsigned short*)take(size_t(NU) * HD * 2);
  float* m1   = (float*)take(size_t(NM) * HD * 4);
  float* aggb = (float*)take(size_t(NU) * HD * 4);
  if (off < stage_end) off = stage_end;
  if (off > ws_size) return;   // workspace too small -> fail loudly

  const int TB = 256;

  // ---- CSR build (bucketed; no global per-node atomics) ----
  hipMemsetAsync(bh, 0, size_t(NBK) * 4, stream);
  histB_kernel<<<512, 256, 0, stream>>>(e_src, e_dst, bh);
  scanB_kernel<<<1, 1024, 0, stream>>>(bh, bbase_m, bbase_u, bcur_m, bcur_u);
  passA_kernel<<<(NE + EPB - 1) / EPB, 1024, 0, stream>>>(e_src, e_dst, bcur_m, bcur_u,
                                                          stage_m, stage_u);
  passB_kernel<<<NBK, 1024, 0, stream>>>(bbase_m, bbase_u, stage_m, stage_u,
                                         csr_m, csr_u, rp_m, rp_u);

  // ---- projections ----
  proj_user_kernel<<<NU / 16, TB, 0, stream>>>(x_user, W_user, b_user, hu);
  proj_movie_kernel<<<NM / 16, TB, 0, stream>>>(x_movie, W_movie, b_movie, hm);

  // ---- layer 1: movie side ----
  agg_mean_kernel<<<(NM + 3) / 4, TB, 0, stream>>>(hu, rp_m, csr_m, aggb, NM);
  sage64_kernel<0><<<(NM + 31) / 32, TB, 0, stream>>>(aggb, hm, Wl1_um, bl1_um, Wr1_um, m1, NM);

  // ---- layer 1: user side ----
  agg_mean_kernel<<<(NU + 3) / 4, TB, 0, stream>>>(hm, rp_u, csr_u, aggb, NU);
  sage64_kernel<1><<<(NU + 31) / 32, TB, 0, stream>>>(aggb, hu, Wl1_mu, bl1_mu, Wr1_mu, u1, NU);

  // ---- layer 2: movie output ----
  agg_mean_kernel<<<(NM + 3) / 4, TB, 0, stream>>>(u1, rp_m, csr_m, aggb, NM);
  out_kernel<<<(NM + 3) / 4, TB, 0, stream>>>(aggb, m1, Wl2_um, bl2_um, Wr2_um, outp, NM);
}

// Round 5
// 574.056 us; speedup vs baseline: 3.0636x; 1.0359x over previous
//
#include <hip/hip_runtime.h>

// ---------------------------------------------------------------------------
// Hetero GraphSAGE (user<->movie). Bucketed CSR build, bf16 gather tables,
// register-tiled SAGE linear + register-tiled movie projection GEMM.
// ---------------------------------------------------------------------------

constexpr int NU = 100000;   // users
constexpr int NM = 50000;    // movies
constexpr int NE = 4000000;  // edges
constexpr int FU = 24;       // user feat
constexpr int FM = 404;      // movie feat
constexpr int HD = 64;       // hidden

constexpr int BSH = 8;                       // bucket = 256 node ids
constexpr int MBK = (NM + 255) >> BSH;       // 196 movie buckets
constexpr int UBK = (NU + 255) >> BSH;       // 391 user buckets
constexpr int NBK = MBK + UBK;               // 587
constexpr int EPB = 8192;                    // edges per passA block (1024 thr x 8)

static inline size_t alignup(size_t x) { return (x + 255) & ~size_t(255); }

__device__ __forceinline__ float bf2f(unsigned short h) {
  return __uint_as_float(((unsigned int)h) << 16);
}
__device__ __forceinline__ unsigned short f2bf(float f) {
  unsigned int u = __float_as_uint(f);
  u = (u + 0x7FFFu + ((u >> 16) & 1u)) >> 16;   // RNE
  return (unsigned short)u;
}
__device__ __forceinline__ float2 unpk(unsigned u) {
  return make_float2(__uint_as_float(u << 16), __uint_as_float(u & 0xFFFF0000u));
}

// ---------------- CSR build ----------------

__global__ __launch_bounds__(256) void histB_kernel(const int* __restrict__ src,
                                                    const int* __restrict__ dst,
                                                    int* __restrict__ bh) {
  __shared__ int h[NBK];
  for (int i = threadIdx.x; i < NBK; i += 256) h[i] = 0;
  __syncthreads();
  int idx = blockIdx.x * 256 + threadIdx.x;
  int stride = gridDim.x * 256;
  for (int i = idx; i < NE; i += stride) {
    atomicAdd(&h[dst[i] >> BSH], 1);
    atomicAdd(&h[MBK + (src[i] >> BSH)], 1);
  }
  __syncthreads();
  for (int i = threadIdx.x; i < NBK; i += 256) {
    int c = h[i];
    if (c) atomicAdd(&bh[i], c);
  }
}

__global__ __launch_bounds__(1024) void scanB_kernel(const int* __restrict__ bh,
                                                     int* __restrict__ bbase_m,
                                                     int* __restrict__ bbase_u,
                                                     int* __restrict__ bcur_m,
                                                     int* __restrict__ bcur_u) {
  __shared__ int tmp[1024];
  int t = threadIdx.x;
  int vm = (t < MBK) ? bh[t] : 0;
  tmp[t] = vm;
  __syncthreads();
  for (int off = 1; off < 1024; off <<= 1) {
    int v = (t >= off) ? tmp[t - off] : 0;
    __syncthreads();
    tmp[t] += v;
    __syncthreads();
  }
  if (t < MBK) {
    int e = tmp[t] - vm;
    bbase_m[t] = e; bcur_m[t] = e;
    if (t == MBK - 1) bbase_m[MBK] = tmp[t];
  }
  __syncthreads();
  int vu = (t < UBK) ? bh[MBK + t] : 0;
  tmp[t] = vu;
  __syncthreads();
  for (int off = 1; off < 1024; off <<= 1) {
    int v = (t >= off) ? tmp[t - off] : 0;
    __syncthreads();
    tmp[t] += v;
    __syncthreads();
  }
  if (t < UBK) {
    int e = tmp[t] - vu;
    bbase_u[t] = e; bcur_u[t] = e;
    if (t == UBK - 1) bbase_u[UBK] = tmp[t];
  }
}

// Pass A: scatter edges into bucket-ordered staging.
// Staged entry: (local_node_id << 24) | payload_node_id (payload < 2^17).
__global__ __launch_bounds__(1024) void passA_kernel(
    const int* __restrict__ src, const int* __restrict__ dst,
    int* __restrict__ bcur_m, int* __restrict__ bcur_u,
    unsigned* __restrict__ stage_m, unsigned* __restrict__ stage_u) {
  __shared__ int hB[NBK];
  int t = threadIdx.x;
  for (int i = t; i < NBK; i += 1024) hB[i] = 0;
  __syncthreads();
  int e0 = blockIdx.x * EPB + t;
  int sv[8], dv[8], rm[8], ru[8];
#pragma unroll
  for (int k = 0; k < 8; ++k) {
    int e = e0 + k * 1024;
    if (e < NE) {
      int s = src[e], d = dst[e];
      sv[k] = s; dv[k] = d;
      rm[k] = atomicAdd(&hB[d >> BSH], 1);
      ru[k] = atomicAdd(&hB[MBK + (s >> BSH)], 1);
    } else {
      sv[k] = -1;
    }
  }
  __syncthreads();
  for (int i = t; i < NBK; i += 1024) {
    int c = hB[i];
    int base = 0;
    if (c) base = (i < MBK) ? atomicAdd(&bcur_m[i], c) : atomicAdd(&bcur_u[i - MBK], c);
    hB[i] = base;
  }
  __syncthreads();
#pragma unroll
  for (int k = 0; k < 8; ++k) {
    if (sv[k] >= 0) {
      int s = sv[k], d = dv[k];
      stage_m[hB[d >> BSH] + rm[k]] = ((unsigned)(d & 255) << 24) | (unsigned)s;
      stage_u[hB[MBK + (s >> BSH)] + ru[k]] = ((unsigned)(s & 255) << 24) | (unsigned)d;
    }
  }
}

// Pass B: per-bucket count + LDS scan -> rp, then fine scatter into CSR.
__global__ __launch_bounds__(1024) void passB_kernel(
    const int* __restrict__ bbase_m, const int* __restrict__ bbase_u,
    const unsigned* __restrict__ stage_m, const unsigned* __restrict__ stage_u,
    int* __restrict__ csr_m, int* __restrict__ csr_u,
    int* __restrict__ rp_m, int* __restrict__ rp_u) {
  __shared__ int cnt[256];
  __shared__ int sc[256];
  int b = blockIdx.x;
  const unsigned* stage; int* csr; int* rp; int idbase, ntot, bb, be;
  if (b < MBK) {
    stage = stage_m; csr = csr_m; rp = rp_m;
    idbase = b << BSH; ntot = NM;
    bb = bbase_m[b]; be = bbase_m[b + 1];
  } else {
    int c = b - MBK;
    stage = stage_u; csr = csr_u; rp = rp_u;
    idbase = c << BSH; ntot = NU;
    bb = bbase_u[c]; be = bbase_u[c + 1];
  }
  int nloc = min(256, ntot - idbase);
  int t = threadIdx.x;
  if (t < 256) cnt[t] = 0;
  __syncthreads();
  for (int j = bb + t; j < be; j += 1024) atomicAdd(&cnt[stage[j] >> 24], 1);
  __syncthreads();
  int c0 = (t < 256) ? cnt[t] : 0;
  if (t < 256) sc[t] = c0;
  __syncthreads();
  for (int off = 1; off < 256; off <<= 1) {
    int v = 0;
    if (t < 256 && t >= off) v = sc[t - off];
    __syncthreads();
    if (t < 256) sc[t] += v;
    __syncthreads();
  }
  if (t < nloc) {
    int e = bb + sc[t] - c0;
    rp[idbase + t] = e;
    cnt[t] = e;                     // reuse as cursor
  }
  if (t == 0 && idbase + nloc == ntot) rp[ntot] = be;
  __syncthreads();
  for (int j = bb + t; j < be; j += 1024) {
    unsigned e = stage[j];
    int pos = atomicAdd(&cnt[e >> 24], 1);
    csr[pos] = (int)(e & 0xFFFFFFu);
  }
}

// ---------------- input projections (write bf16 tables) ----------------

__global__ void proj_user_kernel(const float* __restrict__ xu, const float* __restrict__ Wu,
                                 const float* __restrict__ bu, unsigned short* __restrict__ hu) {
  __shared__ float Wt[FU][HD + 1];
  __shared__ float Xl[16][FU];
  int t = threadIdx.x;
  int lane = t & 63, wg = t >> 6;
  int row0 = blockIdx.x * 16;
  for (int h = wg; h < HD; h += 4)
    if (lane < FU) Wt[lane][h] = Wu[h * FU + lane];
  for (int r = wg; r < 16; r += 4)
    if (lane < FU) Xl[r][lane] = xu[(row0 + r) * FU + lane];
  __syncthreads();
  float b = bu[lane];
  float acc[4] = {0.f, 0.f, 0.f, 0.f};
  for (int k = 0; k < FU; ++k) {
    float w = Wt[k][lane];
#pragma unroll
    for (int j = 0; j < 4; ++j) acc[j] += Xl[wg * 4 + j][k] * w;
  }
#pragma unroll
  for (int j = 0; j < 4; ++j)
    hu[(row0 + wg * 4 + j) * HD + lane] = f2bf(acc[j] + b);
}

// Movie projection: register-tiled GEMM. Block tile = 64 rows x 64 cols,
// thread tile = 4x4. K chunked by 64 through LDS with zero-fill tail.
__global__ __launch_bounds__(256, 2) void proj_movie_kernel(
    const float* __restrict__ xm, const float* __restrict__ Wm,
    const float* __restrict__ bm, unsigned short* __restrict__ hm) {
  __shared__ float Ws[64][65];   // [kk][h]
  __shared__ float Xs[64][65];   // [r][kk]
  int t = threadIdx.x;
  int row0 = blockIdx.x * 64;
  int cl = (t & 15) * 4;         // col group
  int rg = (t >> 4) * 4;         // row group
  float acc[4][4];
#pragma unroll
  for (int j = 0; j < 4; ++j)
#pragma unroll
    for (int c = 0; c < 4; ++c) acc[j][c] = 0.f;

  for (int k0 = 0; k0 < FM; k0 += 64) {
    int kc = min(64, FM - k0);
    __syncthreads();
    // stage W chunk: Ws[kk][h] = Wm[h*FM + k0+kk]
    for (int i = t; i < 4096; i += 256) {
      int h = i >> 6, kk = i & 63;
      Ws[kk][h] = (kk < kc) ? Wm[h * FM + k0 + kk] : 0.f;
    }
    // stage X chunk: Xs[r][kk] = xm[(row0+r)*FM + k0+kk]  (float4)
    for (int i = t; i < 1024; i += 256) {
      int r = i >> 4, c4 = i & 15;
      float4 v = make_float4(0.f, 0.f, 0.f, 0.f);
      if (row0 + r < NM && c4 * 4 < kc)
        v = *(const float4*)(xm + (size_t)(row0 + r) * FM + k0 + c4 * 4);
      *(float4*)&Xs[r][c4 * 4] = v;
    }
    __syncthreads();
#pragma unroll 4
    for (int kk = 0; kk < 64; ++kk) {
      float4 wv = *(const float4*)&Ws[kk][cl];
      float x0 = Xs[rg + 0][kk];
      float x1 = Xs[rg + 1][kk];
      float x2 = Xs[rg + 2][kk];
      float x3 = Xs[rg + 3][kk];
      acc[0][0] += x0 * wv.x; acc[0][1] += x0 * wv.y; acc[0][2] += x0 * wv.z; acc[0][3] += x0 * wv.w;
      acc[1][0] += x1 * wv.x; acc[1][1] += x1 * wv.y; acc[1][2] += x1 * wv.z; acc[1][3] += x1 * wv.w;
      acc[2][0] += x2 * wv.x; acc[2][1] += x2 * wv.y; acc[2][2] += x2 * wv.z; acc[2][3] += x2 * wv.w;
      acc[3][0] += x3 * wv.x; acc[3][1] += x3 * wv.y; acc[3][2] += x3 * wv.z; acc[3][3] += x3 * wv.w;
    }
  }
  float4 bv = *(const float4*)(bm + cl);
#pragma unroll
  for (int j = 0; j < 4; ++j) {
    int row = row0 + rg + j;
    if (row < NM) {
      ushort4 o;
      o.x = f2bf(acc[j][0] + bv.x);
      o.y = f2bf(acc[j][1] + bv.y);
      o.z = f2bf(acc[j][2] + bv.z);
      o.w = f2bf(acc[j][3] + bv.w);
      *(ushort4*)(hm + (size_t)row * HD + cl) = o;
    }
  }
}

// ---------------- mean aggregation: 4 neighbors/wave, 8B/lane gathers ------

__global__ __launch_bounds__(256) void agg_mean_kernel(
    const unsigned short* __restrict__ table, const int* __restrict__ rp,
    const int* __restrict__ csr, float* __restrict__ out, int n) {
  int wid = threadIdx.x >> 6;
  int lane = threadIdx.x & 63;
  int row = blockIdx.x * 4 + wid;
  if (row >= n) return;
  int beg = rp[row], end = rp[row + 1];
  int g = lane >> 4;        // neighbor slot 0..3
  int fq = lane & 15;       // feature quad
  float a0 = 0.f, a1 = 0.f, a2 = 0.f, a3 = 0.f;
  int i = beg;
  for (; i + 8 <= end; i += 8) {
    int n0 = csr[i + g];
    int n1 = csr[i + 4 + g];
    uint2 v0 = *(const uint2*)(table + (size_t)n0 * HD + fq * 4);
    uint2 v1 = *(const uint2*)(table + (size_t)n1 * HD + fq * 4);
    float2 p0 = unpk(v0.x), p1 = unpk(v0.y);
    float2 q0 = unpk(v1.x), q1 = unpk(v1.y);
    a0 += p0.x + q0.x; a1 += p0.y + q0.y;
    a2 += p1.x + q1.x; a3 += p1.y + q1.y;
  }
  for (; i < end; i += 4) {
    int idx = i + g;
    if (idx < end) {
      int nb = csr[idx];
      uint2 v = *(const uint2*)(table + (size_t)nb * HD + fq * 4);
      float2 p0 = unpk(v.x), p1 = unpk(v.y);
      a0 += p0.x; a1 += p0.y; a2 += p1.x; a3 += p1.y;
    }
  }
  a0 += __shfl_xor(a0, 16); a0 += __shfl_xor(a0, 32);
  a1 += __shfl_xor(a1, 16); a1 += __shfl_xor(a1, 32);
  a2 += __shfl_xor(a2, 16); a2 += __shfl_xor(a2, 32);
  a3 += __shfl_xor(a3, 16); a3 += __shfl_xor(a3, 32);
  float inv = 1.0f / fmaxf((float)(end - beg), 1.0f);
  if (lane < 16) {
    float4 o = make_float4(a0 * inv, a1 * inv, a2 * inv, a3 * inv);
    *(float4*)(out + (size_t)row * HD + fq * 4) = o;
  }
}

// ---------------- SAGE linear 64->64 + relu (register-tiled) ----------------

template <int OUTBF>
__global__ __launch_bounds__(256, 3) void sage64_kernel(
    const float* __restrict__ agg, const unsigned short* __restrict__ xd,
    const float* __restrict__ Wl, const float* __restrict__ bl,
    const float* __restrict__ Wr, void* __restrict__ outp, int n) {
  __shared__ float Ws[128][65];     // [k][h], padded
  __shared__ float Xs[32][128];     // [row][k] : k<64 agg, k>=64 x
  int t = threadIdx.x;
  int lane = t & 63, wid = t >> 6;
  int row0 = blockIdx.x * 32;
  for (int i = t; i < 4096; i += 256) {
    int h = i >> 6, k = i & 63;
    Ws[k][h] = Wl[i];
  }
  for (int i = t; i < 4096; i += 256) {
    int h = i >> 6, k = i & 63;
    Ws[64 + k][h] = Wr[i];
  }
  for (int i = t; i < 512; i += 256) {
    int r = i >> 4, c4 = i & 15;
    if (row0 + r < n) {
      float4 v = ((const float4*)(agg + (size_t)(row0 + r) * HD))[c4];
      *(float4*)&Xs[r][c4 * 4] = v;
    }
  }
  for (int i = t; i < 512; i += 256) {
    int r = i >> 4, c4 = i & 15;
    if (row0 + r < n) {
      uint2 v = ((const uint2*)(xd + (size_t)(row0 + r) * HD))[c4];
      float2 p0 = unpk(v.x), p1 = unpk(v.y);
      *(float4*)&Xs[r][64 + c4 * 4] = make_float4(p0.x, p0.y, p1.x, p1.y);
    }
  }
  __syncthreads();
  float acc[8] = {0.f, 0.f, 0.f, 0.f, 0.f, 0.f, 0.f, 0.f};
  int rbase = wid * 8;
#pragma unroll 4
  for (int k = 0; k < 128; ++k) {
    float wv = Ws[k][lane];
#pragma unroll
    for (int j = 0; j < 8; ++j) acc[j] += Xs[rbase + j][k] * wv;
  }
  float b = bl[lane];
#pragma unroll
  for (int j = 0; j < 8; ++j) {
    int row = row0 + rbase + j;
    if (row < n) {
      float v = fmaxf(acc[j] + b, 0.f);
      if (OUTBF) ((unsigned short*)outp)[(size_t)row * HD + lane] = f2bf(v);
      else       ((float*)outp)[(size_t)row * HD + lane] = v;
    }
  }
}

// ---------------- final layer 64->3 on movies ----------------

__global__ void out_kernel(const float* __restrict__ agg2, const float* __restrict__ m1,
                           const float* __restrict__ Wl2, const float* __restrict__ bl2,
                           const float* __restrict__ Wr2, float* __restrict__ out, int n) {
  int wid = threadIdx.x >> 6, lane = threadIdx.x & 63;
  int row = blockIdx.x * 4 + wid;
  if (row >= n) return;
  float a = agg2[row * HD + lane];
  float mm = m1[row * HD + lane];
#pragma unroll
  for (int g = 0; g < 3; ++g) {
    float p = a * Wl2[g * HD + lane] + mm * Wr2[g * HD + lane];
#pragma unroll
    for (int off = 32; off > 0; off >>= 1) p += __shfl_down(p, off);
    if (lane == 0) out[row * 3 + g] = p + bl2[g];
  }
}

// ---------------------------------------------------------------------------

extern "C" void kernel_launch(void* const* d_in, const int* in_sizes, int n_in,
                              void* d_out, int out_size, void* d_ws, size_t ws_size,
                              hipStream_t stream) {
  const float* x_user  = (const float*)d_in[0];
  const float* x_movie = (const float*)d_in[1];
  const int*   e_src   = (const int*)d_in[2];
  const int*   e_dst   = (const int*)d_in[3];
  const float* W_user  = (const float*)d_in[4];
  const float* b_user  = (const float*)d_in[5];
  const float* W_movie = (const float*)d_in[6];
  const float* b_movie = (const float*)d_in[7];
  const float* Wl1_um  = (const float*)d_in[8];
  const float* bl1_um  = (const float*)d_in[9];
  const float* Wr1_um  = (const float*)d_in[10];
  const float* Wl1_mu  = (const float*)d_in[11];
  const float* bl1_mu  = (const float*)d_in[12];
  const float* Wr1_mu  = (const float*)d_in[13];
  const float* Wl2_um  = (const float*)d_in[14];
  const float* bl2_um  = (const float*)d_in[15];
  const float* Wr2_um  = (const float*)d_in[16];
  float* outp = (float*)d_out;

  // ---- workspace carve-up ----
  char* p = (char*)d_ws;
  size_t off = 0;
  auto take = [&](size_t bytes) { void* r = p + off; off += alignup(bytes); return r; };

  int* rp_m    = (int*)take(size_t(NM + 1) * 4);
  int* rp_u    = (int*)take(size_t(NU + 1) * 4);
  int* bh      = (int*)take(size_t(NBK) * 4);
  int* bbase_m = (int*)take(size_t(MBK + 1) * 4);
  int* bbase_u = (int*)take(size_t(UBK + 1) * 4);
  int* bcur_m  = (int*)take(size_t(MBK) * 4);
  int* bcur_u  = (int*)take(size_t(UBK) * 4);
  int* csr_m   = (int*)take(size_t(NE) * 4);
  int* csr_u   = (int*)take(size_t(NE) * 4);

  // overlay: staging (build phase) aliases feature buffers (feature phase)
  size_t ov_base = off;
  unsigned* stage_m = (unsigned*)take(size_t(NE) * 4);
  unsigned* stage_u = (unsigned*)take(size_t(NE) * 4);
  size_t stage_end = off;
  off = ov_base;
  unsigned short* hu = (unsigned short*)take(size_t(NU) * HD * 2);
  unsigned short* hm = (unsigned short*)take(size_t(NM) * HD * 2);
  unsigned short* u1 = (unsigned short*)take(size_t(NU) * HD * 2);
  float* m1   = (float*)take(size_t(NM) * HD * 4);
  float* aggb = (float*)take(size_t(NU) * HD * 4);
  if (off < stage_end) off = stage_end;
  if (off > ws_size) return;

  const int TB = 256;

  // ---- CSR build ----
  hipMemsetAsync(bh, 0, size_t(NBK) * 4, stream);
  histB_kernel<<<512, 256, 0, stream>>>(e_src, e_dst, bh);
  scanB_kernel<<<1, 1024, 0, stream>>>(bh, bbase_m, bbase_u, bcur_m, bcur_u);
  passA_kernel<<<(NE + EPB - 1) / EPB, 1024, 0, stream>>>(e_src, e_dst, bcur_m, bcur_u,
                                                          stage_m, stage_u);
  passB_kernel<<<NBK, 1024, 0, stream>>>(bbase_m, bbase_u, stage_m, stage_u,
                                         csr_m, csr_u, rp_m, rp_u);

  // ---- projections ----
  proj_user_kernel<<<NU / 16, TB, 0, stream>>>(x_user, W_user, b_user, hu);
  proj_movie_kernel<<<(NM + 63) / 64, TB, 0, stream>>>(x_movie, W_movie, b_movie, hm);

  // ---- layer 1: movie side ----
  agg_mean_kernel<<<(NM + 3) / 4, TB, 0, stream>>>(hu, rp_m, csr_m, aggb, NM);
  sage64_kernel<0><<<(NM + 31) / 32, TB, 0, stream>>>(aggb, hm, Wl1_um, bl1_um, Wr1_um, m1, NM);

  // ---- layer 1: user side ----
  agg_mean_kernel<<<(NU + 3) / 4, TB, 0, stream>>>(hm, rp_u, csr_u, aggb, NU);
  sage64_kernel<1><<<(NU + 31) / 32, TB, 0, stream>>>(aggb, hu, Wl1_mu, bl1_mu, Wr1_mu, u1, NU);

  // ---- layer 2: movie output ----
  agg_mean_kernel<<<(NM + 3) / 4, TB, 0, stream>>>(u1, rp_m, csr_m, aggb, NM);
  out_kernel<<<(NM + 3) / 4, TB, 0, stream>>>(aggb, m1, Wl2_um, bl2_um, Wr2_um, outp, NM);
}

// Round 6
// 552.262 us; speedup vs baseline: 3.1845x; 1.0395x over previous
//
#include <hip/hip_runtime.h>

// ---------------------------------------------------------------------------
// Hetero GraphSAGE (user<->movie). Bucketed CSR build, bf16 gather tables,
// register-tiled SAGE linear + register-tiled movie projection GEMM.
// ---------------------------------------------------------------------------

constexpr int NU = 100000;   // users
constexpr int NM = 50000;    // movies
constexpr int NE = 4000000;  // edges
constexpr int FU = 24;       // user feat
constexpr int FM = 404;      // movie feat
constexpr int HD = 64;       // hidden

constexpr int BSH = 8;                       // bucket = 256 node ids
constexpr int MBK = (NM + 255) >> BSH;       // 196 movie buckets
constexpr int UBK = (NU + 255) >> BSH;       // 391 user buckets
constexpr int NBK = MBK + UBK;               // 587
constexpr int EPB = 8192;                    // edges per passA block (1024 thr x 8)

static inline size_t alignup(size_t x) { return (x + 255) & ~size_t(255); }

__device__ __forceinline__ float bf2f(unsigned short h) {
  return __uint_as_float(((unsigned int)h) << 16);
}
__device__ __forceinline__ unsigned short f2bf(float f) {
  unsigned int u = __float_as_uint(f);
  u = (u + 0x7FFFu + ((u >> 16) & 1u)) >> 16;   // RNE
  return (unsigned short)u;
}
__device__ __forceinline__ float2 unpk(unsigned u) {
  return make_float2(__uint_as_float(u << 16), __uint_as_float(u & 0xFFFF0000u));
}

// ---------------- CSR build ----------------

__global__ __launch_bounds__(256) void histB_kernel(const int* __restrict__ src,
                                                    const int* __restrict__ dst,
                                                    int* __restrict__ bh) {
  __shared__ int h[NBK];
  for (int i = threadIdx.x; i < NBK; i += 256) h[i] = 0;
  __syncthreads();
  int idx = blockIdx.x * 256 + threadIdx.x;
  int stride = gridDim.x * 256;
  for (int i = idx; i < NE; i += stride) {
    atomicAdd(&h[dst[i] >> BSH], 1);
    atomicAdd(&h[MBK + (src[i] >> BSH)], 1);
  }
  __syncthreads();
  for (int i = threadIdx.x; i < NBK; i += 256) {
    int c = h[i];
    if (c) atomicAdd(&bh[i], c);
  }
}

__global__ __launch_bounds__(1024) void scanB_kernel(const int* __restrict__ bh,
                                                     int* __restrict__ bbase_m,
                                                     int* __restrict__ bbase_u,
                                                     int* __restrict__ bcur_m,
                                                     int* __restrict__ bcur_u) {
  __shared__ int tmp[1024];
  int t = threadIdx.x;
  int vm = (t < MBK) ? bh[t] : 0;
  tmp[t] = vm;
  __syncthreads();
  for (int off = 1; off < 1024; off <<= 1) {
    int v = (t >= off) ? tmp[t - off] : 0;
    __syncthreads();
    tmp[t] += v;
    __syncthreads();
  }
  if (t < MBK) {
    int e = tmp[t] - vm;
    bbase_m[t] = e; bcur_m[t] = e;
    if (t == MBK - 1) bbase_m[MBK] = tmp[t];
  }
  __syncthreads();
  int vu = (t < UBK) ? bh[MBK + t] : 0;
  tmp[t] = vu;
  __syncthreads();
  for (int off = 1; off < 1024; off <<= 1) {
    int v = (t >= off) ? tmp[t - off] : 0;
    __syncthreads();
    tmp[t] += v;
    __syncthreads();
  }
  if (t < UBK) {
    int e = tmp[t] - vu;
    bbase_u[t] = e; bcur_u[t] = e;
    if (t == UBK - 1) bbase_u[UBK] = tmp[t];
  }
}

// Pass A: scatter edges into bucket-ordered staging.
// Staged entry: (local_node_id << 24) | payload_node_id (payload < 2^17).
__global__ __launch_bounds__(1024) void passA_kernel(
    const int* __restrict__ src, const int* __restrict__ dst,
    int* __restrict__ bcur_m, int* __restrict__ bcur_u,
    unsigned* __restrict__ stage_m, unsigned* __restrict__ stage_u) {
  __shared__ int hB[NBK];
  int t = threadIdx.x;
  for (int i = t; i < NBK; i += 1024) hB[i] = 0;
  __syncthreads();
  int e0 = blockIdx.x * EPB + t;
  int sv[8], dv[8], rm[8], ru[8];
#pragma unroll
  for (int k = 0; k < 8; ++k) {
    int e = e0 + k * 1024;
    if (e < NE) {
      int s = src[e], d = dst[e];
      sv[k] = s; dv[k] = d;
      rm[k] = atomicAdd(&hB[d >> BSH], 1);
      ru[k] = atomicAdd(&hB[MBK + (s >> BSH)], 1);
    } else {
      sv[k] = -1;
    }
  }
  __syncthreads();
  for (int i = t; i < NBK; i += 1024) {
    int c = hB[i];
    int base = 0;
    if (c) base = (i < MBK) ? atomicAdd(&bcur_m[i], c) : atomicAdd(&bcur_u[i - MBK], c);
    hB[i] = base;
  }
  __syncthreads();
#pragma unroll
  for (int k = 0; k < 8; ++k) {
    if (sv[k] >= 0) {
      int s = sv[k], d = dv[k];
      stage_m[hB[d >> BSH] + rm[k]] = ((unsigned)(d & 255) << 24) | (unsigned)s;
      stage_u[hB[MBK + (s >> BSH)] + ru[k]] = ((unsigned)(s & 255) << 24) | (unsigned)d;
    }
  }
}

// Pass B: per-bucket count + LDS scan -> rp, then fine scatter into CSR.
__global__ __launch_bounds__(1024) void passB_kernel(
    const int* __restrict__ bbase_m, const int* __restrict__ bbase_u,
    const unsigned* __restrict__ stage_m, const unsigned* __restrict__ stage_u,
    int* __restrict__ csr_m, int* __restrict__ csr_u,
    int* __restrict__ rp_m, int* __restrict__ rp_u) {
  __shared__ int cnt[256];
  __shared__ int sc[256];
  int b = blockIdx.x;
  const unsigned* stage; int* csr; int* rp; int idbase, ntot, bb, be;
  if (b < MBK) {
    stage = stage_m; csr = csr_m; rp = rp_m;
    idbase = b << BSH; ntot = NM;
    bb = bbase_m[b]; be = bbase_m[b + 1];
  } else {
    int c = b - MBK;
    stage = stage_u; csr = csr_u; rp = rp_u;
    idbase = c << BSH; ntot = NU;
    bb = bbase_u[c]; be = bbase_u[c + 1];
  }
  int nloc = min(256, ntot - idbase);
  int t = threadIdx.x;
  if (t < 256) cnt[t] = 0;
  __syncthreads();
  for (int j = bb + t; j < be; j += 1024) atomicAdd(&cnt[stage[j] >> 24], 1);
  __syncthreads();
  int c0 = (t < 256) ? cnt[t] : 0;
  if (t < 256) sc[t] = c0;
  __syncthreads();
  for (int off = 1; off < 256; off <<= 1) {
    int v = 0;
    if (t < 256 && t >= off) v = sc[t - off];
    __syncthreads();
    if (t < 256) sc[t] += v;
    __syncthreads();
  }
  if (t < nloc) {
    int e = bb + sc[t] - c0;
    rp[idbase + t] = e;
    cnt[t] = e;                     // reuse as cursor
  }
  if (t == 0 && idbase + nloc == ntot) rp[ntot] = be;
  __syncthreads();
  for (int j = bb + t; j < be; j += 1024) {
    unsigned e = stage[j];
    int pos = atomicAdd(&cnt[e >> 24], 1);
    csr[pos] = (int)(e & 0xFFFFFFu);
  }
}

// ---------------- input projections (write bf16 tables) ----------------

__global__ void proj_user_kernel(const float* __restrict__ xu, const float* __restrict__ Wu,
                                 const float* __restrict__ bu, unsigned short* __restrict__ hu) {
  __shared__ float Wt[FU][HD + 1];
  __shared__ float Xl[16][FU];
  int t = threadIdx.x;
  int lane = t & 63, wg = t >> 6;
  int row0 = blockIdx.x * 16;
  for (int h = wg; h < HD; h += 4)
    if (lane < FU) Wt[lane][h] = Wu[h * FU + lane];
  for (int r = wg; r < 16; r += 4)
    if (lane < FU) Xl[r][lane] = xu[(row0 + r) * FU + lane];
  __syncthreads();
  float b = bu[lane];
  float acc[4] = {0.f, 0.f, 0.f, 0.f};
  for (int k = 0; k < FU; ++k) {
    float w = Wt[k][lane];
#pragma unroll
    for (int j = 0; j < 4; ++j) acc[j] += Xl[wg * 4 + j][k] * w;
  }
#pragma unroll
  for (int j = 0; j < 4; ++j)
    hu[(row0 + wg * 4 + j) * HD + lane] = f2bf(acc[j] + b);
}

// Movie projection: register-tiled GEMM. Block tile = 64 rows x 64 cols,
// thread tile = 4x4. K chunked by 64 through LDS with zero-fill tail.
// Pad = +4 floats (stride 68): keeps 16B alignment for b128 ops
// (68*4=272 = 0 mod 16) and rotates banks by 4 per row.
__global__ __launch_bounds__(256, 2) void proj_movie_kernel(
    const float* __restrict__ xm, const float* __restrict__ Wm,
    const float* __restrict__ bm, unsigned short* __restrict__ hm) {
  __shared__ float Ws[64][68];   // [kk][h]
  __shared__ float Xs[64][68];   // [r][kk]
  int t = threadIdx.x;
  int row0 = blockIdx.x * 64;
  int cl = (t & 15) * 4;         // col group
  int rg = (t >> 4) * 4;         // row group
  float acc[4][4];
#pragma unroll
  for (int j = 0; j < 4; ++j)
#pragma unroll
    for (int c = 0; c < 4; ++c) acc[j][c] = 0.f;

  for (int k0 = 0; k0 < FM; k0 += 64) {
    int kc = min(64, FM - k0);
    __syncthreads();
    // stage W chunk: Ws[kk][h] = Wm[h*FM + k0+kk]
    for (int i = t; i < 4096; i += 256) {
      int h = i >> 6, kk = i & 63;
      Ws[kk][h] = (kk < kc) ? Wm[h * FM + k0 + kk] : 0.f;
    }
    // stage X chunk: Xs[r][kk] = xm[(row0+r)*FM + k0+kk]  (float4)
    for (int i = t; i < 1024; i += 256) {
      int r = i >> 4, c4 = i & 15;
      float4 v = make_float4(0.f, 0.f, 0.f, 0.f);
      if (row0 + r < NM && c4 * 4 < kc)
        v = *(const float4*)(xm + (size_t)(row0 + r) * FM + k0 + c4 * 4);
      *(float4*)&Xs[r][c4 * 4] = v;
    }
    __syncthreads();
#pragma unroll 4
    for (int kk = 0; kk < 64; ++kk) {
      float4 wv = *(const float4*)&Ws[kk][cl];
      float x0 = Xs[rg + 0][kk];
      float x1 = Xs[rg + 1][kk];
      float x2 = Xs[rg + 2][kk];
      float x3 = Xs[rg + 3][kk];
      acc[0][0] += x0 * wv.x; acc[0][1] += x0 * wv.y; acc[0][2] += x0 * wv.z; acc[0][3] += x0 * wv.w;
      acc[1][0] += x1 * wv.x; acc[1][1] += x1 * wv.y; acc[1][2] += x1 * wv.z; acc[1][3] += x1 * wv.w;
      acc[2][0] += x2 * wv.x; acc[2][1] += x2 * wv.y; acc[2][2] += x2 * wv.z; acc[2][3] += x2 * wv.w;
      acc[3][0] += x3 * wv.x; acc[3][1] += x3 * wv.y; acc[3][2] += x3 * wv.z; acc[3][3] += x3 * wv.w;
    }
  }
  float4 bv = *(const float4*)(bm + cl);
#pragma unroll
  for (int j = 0; j < 4; ++j) {
    int row = row0 + rg + j;
    if (row < NM) {
      ushort4 o;
      o.x = f2bf(acc[j][0] + bv.x);
      o.y = f2bf(acc[j][1] + bv.y);
      o.z = f2bf(acc[j][2] + bv.z);
      o.w = f2bf(acc[j][3] + bv.w);
      *(ushort4*)(hm + (size_t)row * HD + cl) = o;
    }
  }
}

// ---------------- mean aggregation: 4 neighbors/wave, 8B/lane gathers ------

__global__ __launch_bounds__(256) void agg_mean_kernel(
    const unsigned short* __restrict__ table, const int* __restrict__ rp,
    const int* __restrict__ csr, float* __restrict__ out, int n) {
  int wid = threadIdx.x >> 6;
  int lane = threadIdx.x & 63;
  int row = blockIdx.x * 4 + wid;
  if (row >= n) return;
  int beg = rp[row], end = rp[row + 1];
  int g = lane >> 4;        // neighbor slot 0..3
  int fq = lane & 15;       // feature quad
  float a0 = 0.f, a1 = 0.f, a2 = 0.f, a3 = 0.f;
  int i = beg;
  for (; i + 8 <= end; i += 8) {
    int n0 = csr[i + g];
    int n1 = csr[i + 4 + g];
    uint2 v0 = *(const uint2*)(table + (size_t)n0 * HD + fq * 4);
    uint2 v1 = *(const uint2*)(table + (size_t)n1 * HD + fq * 4);
    float2 p0 = unpk(v0.x), p1 = unpk(v0.y);
    float2 q0 = unpk(v1.x), q1 = unpk(v1.y);
    a0 += p0.x + q0.x; a1 += p0.y + q0.y;
    a2 += p1.x + q1.x; a3 += p1.y + q1.y;
  }
  for (; i < end; i += 4) {
    int idx = i + g;
    if (idx < end) {
      int nb = csr[idx];
      uint2 v = *(const uint2*)(table + (size_t)nb * HD + fq * 4);
      float2 p0 = unpk(v.x), p1 = unpk(v.y);
      a0 += p0.x; a1 += p0.y; a2 += p1.x; a3 += p1.y;
    }
  }
  a0 += __shfl_xor(a0, 16); a0 += __shfl_xor(a0, 32);
  a1 += __shfl_xor(a1, 16); a1 += __shfl_xor(a1, 32);
  a2 += __shfl_xor(a2, 16); a2 += __shfl_xor(a2, 32);
  a3 += __shfl_xor(a3, 16); a3 += __shfl_xor(a3, 32);
  float inv = 1.0f / fmaxf((float)(end - beg), 1.0f);
  if (lane < 16) {
    float4 o = make_float4(a0 * inv, a1 * inv, a2 * inv, a3 * inv);
    *(float4*)(out + (size_t)row * HD + fq * 4) = o;
  }
}

// ---------------- SAGE linear 64->64 + relu (register-tiled) ----------------

template <int OUTBF>
__global__ __launch_bounds__(256, 3) void sage64_kernel(
    const float* __restrict__ agg, const unsigned short* __restrict__ xd,
    const float* __restrict__ Wl, const float* __restrict__ bl,
    const float* __restrict__ Wr, void* __restrict__ outp, int n) {
  __shared__ float Ws[128][65];     // [k][h], padded (scalar reads only)
  __shared__ float Xs[32][128];     // [row][k] : k<64 agg, k>=64 x
  int t = threadIdx.x;
  int lane = t & 63, wid = t >> 6;
  int row0 = blockIdx.x * 32;
  for (int i = t; i < 4096; i += 256) {
    int h = i >> 6, k = i & 63;
    Ws[k][h] = Wl[i];
  }
  for (int i = t; i < 4096; i += 256) {
    int h = i >> 6, k = i & 63;
    Ws[64 + k][h] = Wr[i];
  }
  for (int i = t; i < 512; i += 256) {
    int r = i >> 4, c4 = i & 15;
    if (row0 + r < n) {
      float4 v = ((const float4*)(agg + (size_t)(row0 + r) * HD))[c4];
      *(float4*)&Xs[r][c4 * 4] = v;
    }
  }
  for (int i = t; i < 512; i += 256) {
    int r = i >> 4, c4 = i & 15;
    if (row0 + r < n) {
      uint2 v = ((const uint2*)(xd + (size_t)(row0 + r) * HD))[c4];
      float2 p0 = unpk(v.x), p1 = unpk(v.y);
      *(float4*)&Xs[r][64 + c4 * 4] = make_float4(p0.x, p0.y, p1.x, p1.y);
    }
  }
  __syncthreads();
  float acc[8] = {0.f, 0.f, 0.f, 0.f, 0.f, 0.f, 0.f, 0.f};
  int rbase = wid * 8;
#pragma unroll 4
  for (int k = 0; k < 128; ++k) {
    float wv = Ws[k][lane];
#pragma unroll
    for (int j = 0; j < 8; ++j) acc[j] += Xs[rbase + j][k] * wv;
  }
  float b = bl[lane];
#pragma unroll
  for (int j = 0; j < 8; ++j) {
    int row = row0 + rbase + j;
    if (row < n) {
      float v = fmaxf(acc[j] + b, 0.f);
      if (OUTBF) ((unsigned short*)outp)[(size_t)row * HD + lane] = f2bf(v);
      else       ((float*)outp)[(size_t)row * HD + lane] = v;
    }
  }
}

// ---------------- final layer 64->3 on movies ----------------

__global__ void out_kernel(const float* __restrict__ agg2, const float* __restrict__ m1,
                           const float* __restrict__ Wl2, const float* __restrict__ bl2,
                           const float* __restrict__ Wr2, float* __restrict__ out, int n) {
  int wid = threadIdx.x >> 6, lane = threadIdx.x & 63;
  int row = blockIdx.x * 4 + wid;
  if (row >= n) return;
  float a = agg2[row * HD + lane];
  float mm = m1[row * HD + lane];
#pragma unroll
  for (int g = 0; g < 3; ++g) {
    float p = a * Wl2[g * HD + lane] + mm * Wr2[g * HD + lane];
#pragma unroll
    for (int off = 32; off > 0; off >>= 1) p += __shfl_down(p, off);
    if (lane == 0) out[row * 3 + g] = p + bl2[g];
  }
}

// ---------------------------------------------------------------------------

extern "C" void kernel_launch(void* const* d_in, const int* in_sizes, int n_in,
                              void* d_out, int out_size, void* d_ws, size_t ws_size,
                              hipStream_t stream) {
  const float* x_user  = (const float*)d_in[0];
  const float* x_movie = (const float*)d_in[1];
  const int*   e_src   = (const int*)d_in[2];
  const int*   e_dst   = (const int*)d_in[3];
  const float* W_user  = (const float*)d_in[4];
  const float* b_user  = (const float*)d_in[5];
  const float* W_movie = (const float*)d_in[6];
  const float* b_movie = (const float*)d_in[7];
  const float* Wl1_um  = (const float*)d_in[8];
  const float* bl1_um  = (const float*)d_in[9];
  const float* Wr1_um  = (const float*)d_in[10];
  const float* Wl1_mu  = (const float*)d_in[11];
  const float* bl1_mu  = (const float*)d_in[12];
  const float* Wr1_mu  = (const float*)d_in[13];
  const float* Wl2_um  = (const float*)d_in[14];
  const float* bl2_um  = (const float*)d_in[15];
  const float* Wr2_um  = (const float*)d_in[16];
  float* outp = (float*)d_out;

  // ---- workspace carve-up ----
  char* p = (char*)d_ws;
  size_t off = 0;
  auto take = [&](size_t bytes) { void* r = p + off; off += alignup(bytes); return r; };

  int* rp_m    = (int*)take(size_t(NM + 1) * 4);
  int* rp_u    = (int*)take(size_t(NU + 1) * 4);
  int* bh      = (int*)take(size_t(NBK) * 4);
  int* bbase_m = (int*)take(size_t(MBK + 1) * 4);
  int* bbase_u = (int*)take(size_t(UBK + 1) * 4);
  int* bcur_m  = (int*)take(size_t(MBK) * 4);
  int* bcur_u  = (int*)take(size_t(UBK) * 4);
  int* csr_m   = (int*)take(size_t(NE) * 4);
  int* csr_u   = (int*)take(size_t(NE) * 4);

  // overlay: staging (build phase) aliases feature buffers (feature phase)
  size_t ov_base = off;
  unsigned* stage_m = (unsigned*)take(size_t(NE) * 4);
  unsigned* stage_u = (unsigned*)take(size_t(NE) * 4);
  size_t stage_end = off;
  off = ov_base;
  unsigned short* hu = (unsigned short*)take(size_t(NU) * HD * 2);
  unsigned short* hm = (unsigned short*)take(size_t(NM) * HD * 2);
  unsigned short* u1 = (unsigned short*)take(size_t(NU) * HD * 2);
  float* m1   = (float*)take(size_t(NM) * HD * 4);
  float* aggb = (float*)take(size_t(NU) * HD * 4);
  if (off < stage_end) off = stage_end;
  if (off > ws_size) return;

  const int TB = 256;

  // ---- CSR build ----
  hipMemsetAsync(bh, 0, size_t(NBK) * 4, stream);
  histB_kernel<<<512, 256, 0, stream>>>(e_src, e_dst, bh);
  scanB_kernel<<<1, 1024, 0, stream>>>(bh, bbase_m, bbase_u, bcur_m, bcur_u);
  passA_kernel<<<(NE + EPB - 1) / EPB, 1024, 0, stream>>>(e_src, e_dst, bcur_m, bcur_u,
                                                          stage_m, stage_u);
  passB_kernel<<<NBK, 1024, 0, stream>>>(bbase_m, bbase_u, stage_m, stage_u,
                                         csr_m, csr_u, rp_m, rp_u);

  // ---- projections ----
  proj_user_kernel<<<NU / 16, TB, 0, stream>>>(x_user, W_user, b_user, hu);
  proj_movie_kernel<<<(NM + 63) / 64, TB, 0, stream>>>(x_movie, W_movie, b_movie, hm);

  // ---- layer 1: movie side ----
  agg_mean_kernel<<<(NM + 3) / 4, TB, 0, stream>>>(hu, rp_m, csr_m, aggb, NM);
  sage64_kernel<0><<<(NM + 31) / 32, TB, 0, stream>>>(aggb, hm, Wl1_um, bl1_um, Wr1_um, m1, NM);

  // ---- layer 1: user side ----
  agg_mean_kernel<<<(NU + 3) / 4, TB, 0, stream>>>(hm, rp_u, csr_u, aggb, NU);
  sage64_kernel<1><<<(NU + 31) / 32, TB, 0, stream>>>(aggb, hu, Wl1_mu, bl1_mu, Wr1_mu, u1, NU);

  // ---- layer 2: movie output ----
  agg_mean_kernel<<<(NM + 3) / 4, TB, 0, stream>>>(u1, rp_m, csr_m, aggb, NM);
  out_kernel<<<(NM + 3) / 4, TB, 0, stream>>>(aggb, m1, Wl2_um, bl2_um, Wr2_um, outp, NM);
}